// Round 3
// baseline (420.905 us; speedup 1.0000x reference)
//
#include <hip/hip_runtime.h>
#include <stdint.h>

#define NB 8192
#define ND 2048
#define NE 8
#define NG 4
#define NP 512
#define NH 192

typedef _Float16 half_t;
typedef half_t f16x8 __attribute__((ext_vector_type(8)));
typedef float f32x4 __attribute__((ext_vector_type(4)));

__device__ __forceinline__ void gload16(const void* g, void* l) {
  __builtin_amdgcn_global_load_lds(
      (const __attribute__((address_space(1))) void*)g,
      (__attribute__((address_space(3))) void*)l, 16, 0, 0);
}

// ---------------- x -> fp16 conversion + fp64 row mean ----------------
__global__ __launch_bounds__(256) void k_convert(
    const float* __restrict__ x, half_t* __restrict__ xh, double* __restrict__ qm)
{
  const int b = blockIdx.x;
  const int t = threadIdx.x;
  const float* xr = x + (size_t)b * ND;
  const float4 v0 = ((const float4*)xr)[t * 2];
  const float4 v1 = ((const float4*)xr)[t * 2 + 1];
  float f[8] = {v0.x, v0.y, v0.z, v0.w, v1.x, v1.y, v1.z, v1.w};
  double s = 0.0;
  __align__(16) half_t hb[8];
#pragma unroll
  for (int i = 0; i < 8; i++) { s += (double)f[i]; hb[i] = (half_t)f[i]; }
  *reinterpret_cast<int4*>(xh + (size_t)b * ND + t * 8) = *reinterpret_cast<const int4*>(hb);

#pragma unroll
  for (int m = 32; m >= 1; m >>= 1) s += __shfl_xor(s, m);
  __shared__ double part[4];
  if ((t & 63) == 0) part[t >> 6] = s;
  __syncthreads();
  if (t == 0) qm[b] = (part[0] + part[1] + part[2] + part[3]) / (double)ND;
}

// ---------------- gating: one wave per row, NO atomics ----------------
__global__ __launch_bounds__(256) void k_gate(
    const double* __restrict__ qm,
    const float* __restrict__ Wg, const float* __restrict__ bg,
    const float* __restrict__ Wp, const float* __restrict__ bp,
    const float* __restrict__ Wgg, const float* __restrict__ bgg,
    int* __restrict__ e0a, int* __restrict__ e1a,
    float* __restrict__ w0a, float* __restrict__ w1a)
{
  const int wave = threadIdx.x >> 6;
  const int lane = threadIdx.x & 63;
  const int b = blockIdx.x * 4 + wave;
  const double q = qm[b];

  double part = 0.0;
#pragma unroll
  for (int i = 0; i < 3; i++) {
    int h = lane + i * 64;  // 0..191
    double ang = q * (7.0 * (double)(h + 1));
    part += cos(ang) + sin(ang);
  }
#pragma unroll
  for (int m = 32; m >= 1; m >>= 1) part += __shfl_xor(part, m);
  const double tm = part / (2.0 * (double)NH);
  const double gi1 = 32.0 / 2048.0;  // mean spike rate is a constant (R0 analysis)

  double lg = -1.0e300;
  if (lane < 8) {
    const int e = lane, g = e & 3;
    lg = tm * (double)Wg[e] + gi1 * (double)Wg[NE + e] + (double)bg[e];
    lg -= 0.1 * (tm * (double)Wp[e] + gi1 * (double)Wp[NE + e] + (double)bp[e]);
    lg += tm * (double)Wgg[g] + gi1 * (double)Wgg[NG + g] + (double)bgg[g];
  }
  double mx = lg;
#pragma unroll
  for (int m = 4; m >= 1; m >>= 1) mx = fmax(mx, __shfl_xor(mx, m));
  double pe = 0.0;
  if (lane < 8) pe = exp(lg - mx);
  double ps = pe;
#pragma unroll
  for (int m = 4; m >= 1; m >>= 1) ps += __shfl_xor(ps, m);

  double lgs[8], pes[8];
#pragma unroll
  for (int e = 0; e < 8; e++) { lgs[e] = __shfl(lg, e); pes[e] = __shfl(pe, e); }

  if (lane == 0) {
    int e0 = 0;
    for (int e = 1; e < NE; e++) if (lgs[e] > lgs[e0]) e0 = e;
    int e1 = (e0 == 0) ? 1 : 0;
    for (int e = 0; e < NE; e++) if (e != e0 && lgs[e] > lgs[e1]) e1 = e;
    const double p0 = pes[e0] / ps;
    const double p1 = pes[e1] / ps;
    const double den = p0 + p1 + 1e-9;
    e0a[b] = e0; e1a[b] = e1;
    w0a[b] = (float)(p0 / den);
    w1a[b] = (float)(p1 / den);
  }
}

// ---------------- bucket build: slot-expert buckets + pair buckets ----------------
__global__ __launch_bounds__(256) void k_bucket(
    const int* __restrict__ e0a, const int* __restrict__ e1a,
    const float* __restrict__ w0a, const float* __restrict__ w1a,
    int* __restrict__ rowl, float* __restrict__ wl, int* __restrict__ cnt,
    int* __restrict__ pos0a, int* __restrict__ pos1a,
    int* __restrict__ rowlp, int* __restrict__ cntp)
{
  const int t = threadIdx.x;
  const int r = blockIdx.x * 256 + t;
  __shared__ int hist[16], base[16], cursor[16];
  __shared__ int histp[64], basep[64], cursorp[64];
  if (t < 16) { hist[t] = 0; cursor[t] = 0; }
  if (t < 64) { histp[t] = 0; cursorp[t] = 0; }
  __syncthreads();

  const int e0 = e0a[r], e1 = e1a[r];
  const int p = e0 * 8 + e1;
  atomicAdd(&hist[e0], 1);
  atomicAdd(&hist[8 + e1], 1);
  atomicAdd(&histp[p], 1);
  __syncthreads();
  if (t < 16) base[t] = atomicAdd(&cnt[t], hist[t]);
  if (t < 64) basep[t] = atomicAdd(&cntp[t], histp[t]);
  __syncthreads();

  int p0 = atomicAdd(&cursor[e0], 1);
  int idx0 = base[e0] + p0;
  rowl[e0 * NB + idx0] = r;
  wl[e0 * NB + idx0] = w0a[r];
  pos0a[r] = idx0;

  int p1 = atomicAdd(&cursor[8 + e1], 1);
  int idx1 = base[8 + e1] + p1;
  rowl[(8 + e1) * NB + idx1] = r;
  wl[(8 + e1) * NB + idx1] = w1a[r];
  pos1a[r] = idx1;

  int pp = atomicAdd(&cursorp[p], 1);
  rowlp[p * NB + basep[p] + pp] = r;
}

// ---------------- weight transpose + fp16 convert ----------------
__global__ __launch_bounds__(256) void k_cvt_w(
    const float* __restrict__ W1, const float* __restrict__ W2,
    half_t* __restrict__ w1t, half_t* __restrict__ w2t)
{
  const int which = blockIdx.y;
  const int R = which ? NP : ND;
  const int C = which ? ND : NP;
  const float* src = which ? W2 : W1;
  half_t* dst = which ? w2t : w1t;
  const int tiles_c = C >> 5;
  const int tiles_per_e = (R >> 5) * tiles_c;
  int id = blockIdx.x;
  int e = id / tiles_per_e;
  int rem = id - e * tiles_per_e;
  int tr = rem / tiles_c, tc = rem - tr * tiles_c;
  __shared__ float tile[32][33];
  const int tx = threadIdx.x & 31, ty = threadIdx.x >> 5;
  const float* s = src + (size_t)e * R * C + (size_t)(tr * 32) * C + tc * 32;
#pragma unroll
  for (int i = 0; i < 4; i++)
    tile[ty + i * 8][tx] = s[(size_t)(ty + i * 8) * C + tx];
  __syncthreads();
  half_t* d = dst + (size_t)e * R * C + (size_t)(tc * 32) * R + tr * 32;
#pragma unroll
  for (int i = 0; i < 4; i++)
    d[(size_t)(ty + i * 8) * R + tx] = (half_t)tile[tx][ty + i * 8];
}

// ---------------- prefix + compact work-item lists ----------------
__global__ void k_prefix(const int* __restrict__ cnt, const int* __restrict__ cntp,
                         int* __restrict__ pbase,
                         int* __restrict__ i16b, int* __restrict__ i16m, int* __restrict__ n16,
                         int* __restrict__ ipp, int* __restrict__ ipm, int* __restrict__ np)
{
  if (threadIdx.x == 0 && blockIdx.x == 0) {
    int s = 0;
    for (int i = 0; i < 16; i++) { pbase[i] = s; s += cnt[i]; }
    int t = 0;
    for (int b = 0; b < 16; b++)
      for (int m0 = 0; m0 < cnt[b]; m0 += 128) { i16b[t] = b; i16m[t] = m0; t++; }
    *n16 = t;
    t = 0;
    for (int p = 0; p < 64; p++)
      for (int m0 = 0; m0 < cntp[p]; m0 += 128) { ipp[t] = p; ipm[t] = m0; t++; }
    *np = t;
  }
}

// ---------------- GEMM1: H = w * relu(gather(x) @ W1[e] + b1[e]) ----------------
// R3: BK=64 (rounds 64->32), A-only LDS 3-deep pipeline (48KB -> 3 blocks/CU,
// __launch_bounds__(256,3)), B loaded DIRECT to registers (L2-hot, compiler-
// scheduled; manual vmcnt counts stay valid: issue-order drain + loads can't
// cross "memory" asm). A bank-swizzle: chunk ^= row&7 on pre-swizzled global
// source and ds_read slot (rows are 128B -> would be full bank wrap).
// R2 counters: VALUBusy 8%, MfmaUtil 18% -> per-round wait chain dominates;
// this halves round count and doubles absolute prefetch distance.
__global__ __launch_bounds__(256, 3) void k_gemm1(
    const half_t* __restrict__ xh, const half_t* __restrict__ w1t,
    const float* __restrict__ b1,
    const int* __restrict__ rowl, const float* __restrict__ wl,
    const int* __restrict__ cnt, const int* __restrict__ pbase,
    const int* __restrict__ i16b, const int* __restrict__ i16m,
    const int* __restrict__ n16, half_t* __restrict__ Hbuf)
{
  const int wi = blockIdx.y;
  if (wi >= *n16) return;
  const int bucket = i16b[wi];
  const int m0 = i16m[wi];
  const int count = cnt[bucket];
  const int e = bucket & 7;
  const int n0 = blockIdx.x * 128;
  const int t = threadIdx.x;

  __shared__ __align__(16) half_t As[3][128 * 64];
  __shared__ int rows_s[128];
  __shared__ float ws_s[128];

  if (t < 128) {
    int mi = m0 + t;
    int idx = bucket * NB + (mi < count ? mi : m0);
    rows_s[t] = rowl[idx];
    ws_s[t] = wl[idx];
  }
  __syncthreads();

  const int w = t >> 6, lane = t & 63;
  // A staging: thread covers rows {i*32 + w*8 + (lane>>3)}, chunk (lane&7)^(lane>>3)
  const int srow = (w << 3) + (lane >> 3);
  const int sch = (lane & 7) ^ (lane >> 3);
  const half_t* sa0 = xh + (size_t)rows_s[srow] * ND + sch * 8;
  const half_t* sa1 = xh + (size_t)rows_s[32 + srow] * ND + sch * 8;
  const half_t* sa2 = xh + (size_t)rows_s[64 + srow] * ND + sch * 8;
  const half_t* sa3 = xh + (size_t)rows_s[96 + srow] * ND + sch * 8;

  const int wr = w >> 1, wc = w & 1;
  const int lrow = lane & 15, lk = lane >> 4;
  const half_t* w1te = w1t + (size_t)e * NP * ND;
  const half_t* pB0 = w1te + (size_t)(n0 + wc * 64 + 0  + lrow) * ND + lk * 8;
  const half_t* pB1 = w1te + (size_t)(n0 + wc * 64 + 16 + lrow) * ND + lk * 8;
  const half_t* pB2 = w1te + (size_t)(n0 + wc * 64 + 32 + lrow) * ND + lk * 8;
  const half_t* pB3 = w1te + (size_t)(n0 + wc * 64 + 48 + lrow) * ND + lk * 8;

  f32x4 acc[4][4];
#pragma unroll
  for (int i = 0; i < 4; i++)
#pragma unroll
    for (int j = 0; j < 4; j++) {
      acc[i][j][0] = 0.f; acc[i][j][1] = 0.f; acc[i][j][2] = 0.f; acc[i][j][3] = 0.f;
    }

  const int NT = ND / 64;  // 32 rounds

  auto stage = [&](int bi, int tt) {
    const int kk = tt * 64;  // halfs; byte offset <= 3968, imm-foldable
    half_t* ld = &As[bi][t * 8];
    gload16(sa0 + kk, ld);
    gload16(sa1 + kk, ld + 2048);
    gload16(sa2 + kk, ld + 4096);
    gload16(sa3 + kk, ld + 6144);
  };
  auto compute = [&](int bi, int tt) {
#pragma unroll
    for (int ks = 0; ks < 2; ks++) {
      f16x8 af[4], bf[4];
#pragma unroll
      for (int i = 0; i < 4; i++) {
        const int r = wr * 64 + i * 16 + lrow;
        const int slot = (ks * 4 + lk) ^ (lrow & 7);
        af[i] = *reinterpret_cast<const f16x8*>(&As[bi][r * 64 + slot * 8]);
      }
      const int ko = tt * 64 + ks * 32;
      bf[0] = *reinterpret_cast<const f16x8*>(pB0 + ko);
      bf[1] = *reinterpret_cast<const f16x8*>(pB1 + ko);
      bf[2] = *reinterpret_cast<const f16x8*>(pB2 + ko);
      bf[3] = *reinterpret_cast<const f16x8*>(pB3 + ko);
#pragma unroll
      for (int mi = 0; mi < 4; mi++)
#pragma unroll
        for (int ni = 0; ni < 4; ni++)
          acc[mi][ni] = __builtin_amdgcn_mfma_f32_16x16x32_f16(af[mi], bf[ni], acc[mi][ni], 0, 0, 0);
    }
  };

  stage(0, 0);
  stage(1, 1);
  asm volatile("s_waitcnt vmcnt(4)" ::: "memory");
  __builtin_amdgcn_s_barrier();
#pragma unroll
  for (int tt = 0; tt < NT; ++tt) {
    if (tt + 2 < NT) stage((tt + 2) % 3, tt + 2);
    compute(tt % 3, tt);
    if (tt + 1 < NT) {
      if (tt + 2 < NT) asm volatile("s_waitcnt vmcnt(4) lgkmcnt(0)" ::: "memory");
      else             asm volatile("s_waitcnt vmcnt(0) lgkmcnt(0)" ::: "memory");
      __builtin_amdgcn_s_barrier();
    }
  }

  const int pb = pbase[bucket];
#pragma unroll
  for (int mi = 0; mi < 4; mi++) {
#pragma unroll
    for (int i = 0; i < 4; i++) {
      int lm = wr * 64 + mi * 16 + lk * 4 + i;
      if (m0 + lm < count) {
        size_t prow = (size_t)(pb + m0 + lm) * NP;
        float wcoef = ws_s[lm];
#pragma unroll
        for (int ni = 0; ni < 4; ni++) {
          int col = n0 + wc * 64 + ni * 16 + lrow;
          float v = acc[mi][ni][i] + b1[e * NP + col];
          v = v > 0.f ? v : 0.f;
          Hbuf[prow + col] = (half_t)(v * wcoef);  // pre-scale by gate weight
        }
      }
    }
  }
}

// ---- GEMM2 (pair-fused): out[r] = H0w@W2[e0] + H1w@W2[e1] + w0*b2[e0] + w1*b2[e1] ----
// R3: same restructure. NT = 16 rounds (8 per segment at BK=64).
__global__ __launch_bounds__(256, 3) void k_gemm2p(
    const half_t* __restrict__ Hbuf, const half_t* __restrict__ w2t,
    const float* __restrict__ b2,
    const int* __restrict__ rowlp, const int* __restrict__ cntp,
    const int* __restrict__ pbase,
    const int* __restrict__ pos0a, const int* __restrict__ pos1a,
    const float* __restrict__ w0a, const float* __restrict__ w1a,
    const int* __restrict__ ipp, const int* __restrict__ ipm,
    const int* __restrict__ np, float* __restrict__ out)
{
  const int wi = blockIdx.y;
  if (wi >= *np) return;
  const int p = ipp[wi];
  const int m0 = ipm[wi];
  const int count = cntp[p];
  const int e0 = p >> 3, e1 = p & 7;
  const int n0 = blockIdx.x * 128;
  const int t = threadIdx.x;

  __shared__ __align__(16) half_t As[3][128 * 64];
  __shared__ int h0_s[128], h1_s[128], rs_s[128];
  __shared__ float w0_s[128], w1_s[128];

  if (t < 128) {
    int mi = m0 + t;
    int r = rowlp[p * NB + (mi < count ? mi : m0)];
    rs_s[t] = r;
    h0_s[t] = pbase[e0] + pos0a[r];
    h1_s[t] = pbase[8 + e1] + pos1a[r];
    w0_s[t] = w0a[r];
    w1_s[t] = w1a[r];
  }
  __syncthreads();

  const int w = t >> 6, lane = t & 63;
  const int srow = (w << 3) + (lane >> 3);
  const int sch = (lane & 7) ^ (lane >> 3);
  const half_t* sa00 = Hbuf + (size_t)h0_s[srow] * NP + sch * 8;
  const half_t* sa01 = Hbuf + (size_t)h0_s[32 + srow] * NP + sch * 8;
  const half_t* sa02 = Hbuf + (size_t)h0_s[64 + srow] * NP + sch * 8;
  const half_t* sa03 = Hbuf + (size_t)h0_s[96 + srow] * NP + sch * 8;
  const half_t* sa10 = Hbuf + (size_t)h1_s[srow] * NP + sch * 8;
  const half_t* sa11 = Hbuf + (size_t)h1_s[32 + srow] * NP + sch * 8;
  const half_t* sa12 = Hbuf + (size_t)h1_s[64 + srow] * NP + sch * 8;
  const half_t* sa13 = Hbuf + (size_t)h1_s[96 + srow] * NP + sch * 8;

  const int wr = w >> 1, wc = w & 1;
  const int lrow = lane & 15, lk = lane >> 4;
  const half_t* w2e0 = w2t + (size_t)e0 * ND * NP;
  const half_t* w2e1 = w2t + (size_t)e1 * ND * NP;
  const half_t* pB00 = w2e0 + (size_t)(n0 + wc * 64 + 0  + lrow) * NP + lk * 8;
  const half_t* pB01 = w2e0 + (size_t)(n0 + wc * 64 + 16 + lrow) * NP + lk * 8;
  const half_t* pB02 = w2e0 + (size_t)(n0 + wc * 64 + 32 + lrow) * NP + lk * 8;
  const half_t* pB03 = w2e0 + (size_t)(n0 + wc * 64 + 48 + lrow) * NP + lk * 8;
  const half_t* pB10 = w2e1 + (size_t)(n0 + wc * 64 + 0  + lrow) * NP + lk * 8;
  const half_t* pB11 = w2e1 + (size_t)(n0 + wc * 64 + 16 + lrow) * NP + lk * 8;
  const half_t* pB12 = w2e1 + (size_t)(n0 + wc * 64 + 32 + lrow) * NP + lk * 8;
  const half_t* pB13 = w2e1 + (size_t)(n0 + wc * 64 + 48 + lrow) * NP + lk * 8;

  f32x4 acc[4][4];
#pragma unroll
  for (int i = 0; i < 4; i++)
#pragma unroll
    for (int j = 0; j < 4; j++) {
      acc[i][j][0] = 0.f; acc[i][j][1] = 0.f; acc[i][j][2] = 0.f; acc[i][j][3] = 0.f;
    }

  const int NT = 16;  // 2 segments x 8 rounds (BK=64 over NP=512)

  auto stage = [&](int bi, int tt) {
    const int kk = (tt & 7) * 64;
    half_t* ld = &As[bi][t * 8];
    if (tt & 8) {
      gload16(sa10 + kk, ld);
      gload16(sa11 + kk, ld + 2048);
      gload16(sa12 + kk, ld + 4096);
      gload16(sa13 + kk, ld + 6144);
    } else {
      gload16(sa00 + kk, ld);
      gload16(sa01 + kk, ld + 2048);
      gload16(sa02 + kk, ld + 4096);
      gload16(sa03 + kk, ld + 6144);
    }
  };
  auto compute = [&](int bi, int tt) {
#pragma unroll
    for (int ks = 0; ks < 2; ks++) {
      f16x8 af[4], bf[4];
#pragma unroll
      for (int i = 0; i < 4; i++) {
        const int r = wr * 64 + i * 16 + lrow;
        const int slot = (ks * 4 + lk) ^ (lrow & 7);
        af[i] = *reinterpret_cast<const f16x8*>(&As[bi][r * 64 + slot * 8]);
      }
      const int ko = (tt & 7) * 64 + ks * 32;
      if (tt & 8) {
        bf[0] = *reinterpret_cast<const f16x8*>(pB10 + ko);
        bf[1] = *reinterpret_cast<const f16x8*>(pB11 + ko);
        bf[2] = *reinterpret_cast<const f16x8*>(pB12 + ko);
        bf[3] = *reinterpret_cast<const f16x8*>(pB13 + ko);
      } else {
        bf[0] = *reinterpret_cast<const f16x8*>(pB00 + ko);
        bf[1] = *reinterpret_cast<const f16x8*>(pB01 + ko);
        bf[2] = *reinterpret_cast<const f16x8*>(pB02 + ko);
        bf[3] = *reinterpret_cast<const f16x8*>(pB03 + ko);
      }
#pragma unroll
      for (int mi = 0; mi < 4; mi++)
#pragma unroll
        for (int ni = 0; ni < 4; ni++)
          acc[mi][ni] = __builtin_amdgcn_mfma_f32_16x16x32_f16(af[mi], bf[ni], acc[mi][ni], 0, 0, 0);
    }
  };

  stage(0, 0);
  stage(1, 1);
  asm volatile("s_waitcnt vmcnt(4)" ::: "memory");
  __builtin_amdgcn_s_barrier();
#pragma unroll
  for (int tt = 0; tt < NT; ++tt) {
    if (tt + 2 < NT) stage((tt + 2) % 3, tt + 2);
    compute(tt % 3, tt);
    if (tt + 1 < NT) {
      if (tt + 2 < NT) asm volatile("s_waitcnt vmcnt(4) lgkmcnt(0)" ::: "memory");
      else             asm volatile("s_waitcnt vmcnt(0) lgkmcnt(0)" ::: "memory");
      __builtin_amdgcn_s_barrier();
    }
  }

  // epilogue: single write of the combined row
  float b20[4], b21[4];
#pragma unroll
  for (int ni = 0; ni < 4; ni++) {
    int col = n0 + wc * 64 + ni * 16 + lrow;
    b20[ni] = b2[e0 * ND + col];
    b21[ni] = b2[e1 * ND + col];
  }
#pragma unroll
  for (int mi = 0; mi < 4; mi++) {
#pragma unroll
    for (int i = 0; i < 4; i++) {
      int lm = wr * 64 + mi * 16 + lk * 4 + i;
      if (m0 + lm < count) {
        int r = rs_s[lm];
        float wb0 = w0_s[lm], wb1 = w1_s[lm];
        float* orow = out + (size_t)r * ND;
#pragma unroll
        for (int ni = 0; ni < 4; ni++) {
          int col = n0 + wc * 64 + ni * 16 + lrow;
          orow[col] = acc[mi][ni][i] + wb0 * b20[ni] + wb1 * b21[ni];
        }
      }
    }
  }
}

extern "C" void kernel_launch(void* const* d_in, const int* in_sizes, int n_in,
                              void* d_out, int out_size, void* d_ws, size_t ws_size,
                              hipStream_t stream)
{
  const float* x   = (const float*)d_in[0];
  const float* Wg  = (const float*)d_in[1];
  const float* bg  = (const float*)d_in[2];
  const float* Wp  = (const float*)d_in[3];
  const float* bp  = (const float*)d_in[4];
  const float* Wgg = (const float*)d_in[5];
  const float* bgg = (const float*)d_in[6];
  const float* W1  = (const float*)d_in[7];
  const float* b1  = (const float*)d_in[8];
  const float* W2  = (const float*)d_in[9];
  const float* b2  = (const float*)d_in[10];
  float* out = (float*)d_out;

  char* ws = (char*)d_ws;
  size_t off = 0;
  const size_t OFF_XH   = off; off += (size_t)NB * ND * 2;              // 32 MB
  const size_t OFF_W1T  = off; off += (size_t)NE * NP * ND * 2;         // 16 MB
  const size_t OFF_W2T  = off; off += (size_t)NE * ND * NP * 2;         // 16 MB
  const size_t OFF_H    = off; off += (size_t)(2 * NB + 128) * NP * 2;  // ~17 MB
  const size_t OFF_ROWL = off; off += (size_t)16 * NB * 4;
  const size_t OFF_WL   = off; off += (size_t)16 * NB * 4;
  const size_t OFF_ROWLP= off; off += (size_t)64 * NB * 4;              // 2 MB
  const size_t OFF_CNT  = off; off += 64;
  const size_t OFF_CNTP = off; off += 256;
  const size_t OFF_PB   = off; off += 64;
  const size_t OFF_QM   = off; off += (size_t)NB * 8;
  const size_t OFF_E0   = off; off += (size_t)NB * 4;
  const size_t OFF_E1   = off; off += (size_t)NB * 4;
  const size_t OFF_W0   = off; off += (size_t)NB * 4;
  const size_t OFF_W1A  = off; off += (size_t)NB * 4;
  const size_t OFF_POS0 = off; off += (size_t)NB * 4;
  const size_t OFF_POS1 = off; off += (size_t)NB * 4;
  const size_t OFF_I16B = off; off += 1024;
  const size_t OFF_I16M = off; off += 1024;
  const size_t OFF_N16  = off; off += 64;
  const size_t OFF_IPP  = off; off += 1024;
  const size_t OFF_IPM  = off; off += 1024;
  const size_t OFF_NP   = off; off += 64;

  half_t* xh   = (half_t*)(ws + OFF_XH);
  half_t* w1t  = (half_t*)(ws + OFF_W1T);
  half_t* w2t  = (half_t*)(ws + OFF_W2T);
  half_t* Hbuf = (half_t*)(ws + OFF_H);
  int*    rowl = (int*)(ws + OFF_ROWL);
  float*  wl   = (float*)(ws + OFF_WL);
  int*    rowlp= (int*)(ws + OFF_ROWLP);
  int*    cnt  = (int*)(ws + OFF_CNT);
  int*    cntp = (int*)(ws + OFF_CNTP);
  int*    pb   = (int*)(ws + OFF_PB);
  double* qm   = (double*)(ws + OFF_QM);
  int*    e0a  = (int*)(ws + OFF_E0);
  int*    e1a  = (int*)(ws + OFF_E1);
  float*  w0a  = (float*)(ws + OFF_W0);
  float*  w1a  = (float*)(ws + OFF_W1A);
  int*    pos0a= (int*)(ws + OFF_POS0);
  int*    pos1a= (int*)(ws + OFF_POS1);
  int*    i16b = (int*)(ws + OFF_I16B);
  int*    i16m = (int*)(ws + OFF_I16M);
  int*    n16  = (int*)(ws + OFF_N16);
  int*    ipp  = (int*)(ws + OFF_IPP);
  int*    ipm  = (int*)(ws + OFF_IPM);
  int*    np   = (int*)(ws + OFF_NP);

  hipMemsetAsync(cnt, 0, 64 + 256, stream);  // cnt + cntp are contiguous
  k_convert<<<NB, 256, 0, stream>>>(x, xh, qm);
  k_cvt_w<<<dim3(8192, 2, 1), 256, 0, stream>>>(W1, W2, w1t, w2t);
  k_gate<<<NB / 4, 256, 0, stream>>>(qm, Wg, bg, Wp, bp, Wgg, bgg, e0a, e1a, w0a, w1a);
  k_bucket<<<NB / 256, 256, 0, stream>>>(e0a, e1a, w0a, w1a, rowl, wl, cnt,
                                         pos0a, pos1a, rowlp, cntp);
  k_prefix<<<1, 64, 0, stream>>>(cnt, cntp, pb, i16b, i16m, n16, ipp, ipm, np);
  // n16 worst case: 16384/128 + 16 partial tiles = 144
  k_gemm1<<<dim3(4, 144, 1), 256, 0, stream>>>(xh, w1t, b1, rowl, wl, cnt, pb,
                                               i16b, i16m, n16, Hbuf);
  // np worst case: 8192/128 + 64 partial tiles = 128
  k_gemm2p<<<dim3(16, 128, 1), 256, 0, stream>>>(Hbuf, w2t, b2, rowlp, cntp, pb,
                                                 pos0a, pos1a, w0a, w1a, ipp, ipm, np, out);
}

// Round 5
// 360.733 us; speedup vs baseline: 1.1668x; 1.1668x over previous
//
#include <hip/hip_runtime.h>
#include <stdint.h>

#define NB 8192
#define ND 2048
#define NE 8
#define NG 4
#define NP 512
#define NH 192

typedef _Float16 half_t;
typedef half_t f16x8 __attribute__((ext_vector_type(8)));
typedef float f32x4 __attribute__((ext_vector_type(4)));

__device__ __forceinline__ void gload16(const void* g, void* l) {
  __builtin_amdgcn_global_load_lds(
      (const __attribute__((address_space(1))) void*)g,
      (__attribute__((address_space(3))) void*)l, 16, 0, 0);
}

// ---------------- x -> fp16 conversion + fp64 row mean ----------------
__global__ __launch_bounds__(256) void k_convert(
    const float* __restrict__ x, half_t* __restrict__ xh, double* __restrict__ qm)
{
  const int b = blockIdx.x;
  const int t = threadIdx.x;
  const float* xr = x + (size_t)b * ND;
  const float4 v0 = ((const float4*)xr)[t * 2];
  const float4 v1 = ((const float4*)xr)[t * 2 + 1];
  float f[8] = {v0.x, v0.y, v0.z, v0.w, v1.x, v1.y, v1.z, v1.w};
  double s = 0.0;
  __align__(16) half_t hb[8];
#pragma unroll
  for (int i = 0; i < 8; i++) { s += (double)f[i]; hb[i] = (half_t)f[i]; }
  *reinterpret_cast<int4*>(xh + (size_t)b * ND + t * 8) = *reinterpret_cast<const int4*>(hb);

#pragma unroll
  for (int m = 32; m >= 1; m >>= 1) s += __shfl_xor(s, m);
  __shared__ double part[4];
  if ((t & 63) == 0) part[t >> 6] = s;
  __syncthreads();
  if (t == 0) qm[b] = (part[0] + part[1] + part[2] + part[3]) / (double)ND;
}

// ---------------- gating: one wave per row, NO atomics ----------------
__global__ __launch_bounds__(256) void k_gate(
    const double* __restrict__ qm,
    const float* __restrict__ Wg, const float* __restrict__ bg,
    const float* __restrict__ Wp, const float* __restrict__ bp,
    const float* __restrict__ Wgg, const float* __restrict__ bgg,
    int* __restrict__ e0a, int* __restrict__ e1a,
    float* __restrict__ w0a, float* __restrict__ w1a)
{
  const int wave = threadIdx.x >> 6;
  const int lane = threadIdx.x & 63;
  const int b = blockIdx.x * 4 + wave;
  const double q = qm[b];

  double part = 0.0;
#pragma unroll
  for (int i = 0; i < 3; i++) {
    int h = lane + i * 64;  // 0..191
    double ang = q * (7.0 * (double)(h + 1));
    part += cos(ang) + sin(ang);
  }
#pragma unroll
  for (int m = 32; m >= 1; m >>= 1) part += __shfl_xor(part, m);
  const double tm = part / (2.0 * (double)NH);
  const double gi1 = 32.0 / 2048.0;  // mean spike rate is a constant (R0 analysis)

  double lg = -1.0e300;
  if (lane < 8) {
    const int e = lane, g = e & 3;
    lg = tm * (double)Wg[e] + gi1 * (double)Wg[NE + e] + (double)bg[e];
    lg -= 0.1 * (tm * (double)Wp[e] + gi1 * (double)Wp[NE + e] + (double)bp[e]);
    lg += tm * (double)Wgg[g] + gi1 * (double)Wgg[NG + g] + (double)bgg[g];
  }
  double mx = lg;
#pragma unroll
  for (int m = 4; m >= 1; m >>= 1) mx = fmax(mx, __shfl_xor(mx, m));
  double pe = 0.0;
  if (lane < 8) pe = exp(lg - mx);
  double ps = pe;
#pragma unroll
  for (int m = 4; m >= 1; m >>= 1) ps += __shfl_xor(ps, m);

  double lgs[8], pes[8];
#pragma unroll
  for (int e = 0; e < 8; e++) { lgs[e] = __shfl(lg, e); pes[e] = __shfl(pe, e); }

  if (lane == 0) {
    int e0 = 0;
    for (int e = 1; e < NE; e++) if (lgs[e] > lgs[e0]) e0 = e;
    int e1 = (e0 == 0) ? 1 : 0;
    for (int e = 0; e < NE; e++) if (e != e0 && lgs[e] > lgs[e1]) e1 = e;
    const double p0 = pes[e0] / ps;
    const double p1 = pes[e1] / ps;
    const double den = p0 + p1 + 1e-9;
    e0a[b] = e0; e1a[b] = e1;
    w0a[b] = (float)(p0 / den);
    w1a[b] = (float)(p1 / den);
  }
}

// ---------------- bucket build: slot-expert buckets + pair buckets ----------------
__global__ __launch_bounds__(256) void k_bucket(
    const int* __restrict__ e0a, const int* __restrict__ e1a,
    const float* __restrict__ w0a, const float* __restrict__ w1a,
    int* __restrict__ rowl, float* __restrict__ wl, int* __restrict__ cnt,
    int* __restrict__ pos0a, int* __restrict__ pos1a,
    int* __restrict__ rowlp, int* __restrict__ cntp)
{
  const int t = threadIdx.x;
  const int r = blockIdx.x * 256 + t;
  __shared__ int hist[16], base[16], cursor[16];
  __shared__ int histp[64], basep[64], cursorp[64];
  if (t < 16) { hist[t] = 0; cursor[t] = 0; }
  if (t < 64) { histp[t] = 0; cursorp[t] = 0; }
  __syncthreads();

  const int e0 = e0a[r], e1 = e1a[r];
  const int p = e0 * 8 + e1;
  atomicAdd(&hist[e0], 1);
  atomicAdd(&hist[8 + e1], 1);
  atomicAdd(&histp[p], 1);
  __syncthreads();
  if (t < 16) base[t] = atomicAdd(&cnt[t], hist[t]);
  if (t < 64) basep[t] = atomicAdd(&cntp[t], histp[t]);
  __syncthreads();

  int p0 = atomicAdd(&cursor[e0], 1);
  int idx0 = base[e0] + p0;
  rowl[e0 * NB + idx0] = r;
  wl[e0 * NB + idx0] = w0a[r];
  pos0a[r] = idx0;

  int p1 = atomicAdd(&cursor[8 + e1], 1);
  int idx1 = base[8 + e1] + p1;
  rowl[(8 + e1) * NB + idx1] = r;
  wl[(8 + e1) * NB + idx1] = w1a[r];
  pos1a[r] = idx1;

  int pp = atomicAdd(&cursorp[p], 1);
  rowlp[p * NB + basep[p] + pp] = r;
}

// ---------------- weight transpose + fp16 convert ----------------
__global__ __launch_bounds__(256) void k_cvt_w(
    const float* __restrict__ W1, const float* __restrict__ W2,
    half_t* __restrict__ w1t, half_t* __restrict__ w2t)
{
  const int which = blockIdx.y;
  const int R = which ? NP : ND;
  const int C = which ? ND : NP;
  const float* src = which ? W2 : W1;
  half_t* dst = which ? w2t : w1t;
  const int tiles_c = C >> 5;
  const int tiles_per_e = (R >> 5) * tiles_c;
  int id = blockIdx.x;
  int e = id / tiles_per_e;
  int rem = id - e * tiles_per_e;
  int tr = rem / tiles_c, tc = rem - tr * tiles_c;
  __shared__ float tile[32][33];
  const int tx = threadIdx.x & 31, ty = threadIdx.x >> 5;
  const float* s = src + (size_t)e * R * C + (size_t)(tr * 32) * C + tc * 32;
#pragma unroll
  for (int i = 0; i < 4; i++)
    tile[ty + i * 8][tx] = s[(size_t)(ty + i * 8) * C + tx];
  __syncthreads();
  half_t* d = dst + (size_t)e * R * C + (size_t)(tc * 32) * R + tr * 32;
#pragma unroll
  for (int i = 0; i < 4; i++)
    d[(size_t)(ty + i * 8) * R + tx] = (half_t)tile[tx][ty + i * 8];
}

// ---------------- prefix + compact work-item lists ----------------
__global__ void k_prefix(const int* __restrict__ cnt, const int* __restrict__ cntp,
                         int* __restrict__ pbase,
                         int* __restrict__ i16b, int* __restrict__ i16m, int* __restrict__ n16,
                         int* __restrict__ ipp, int* __restrict__ ipm, int* __restrict__ np)
{
  if (threadIdx.x == 0 && blockIdx.x == 0) {
    int s = 0;
    for (int i = 0; i < 16; i++) { pbase[i] = s; s += cnt[i]; }
    int t = 0;
    for (int b = 0; b < 16; b++)
      for (int m0 = 0; m0 < cnt[b]; m0 += 128) { i16b[t] = b; i16m[t] = m0; t++; }
    *n16 = t;
    t = 0;
    for (int p = 0; p < 64; p++)
      for (int m0 = 0; m0 < cntp[p]; m0 += 128) { ipp[t] = p; ipm[t] = m0; t++; }
    *np = t;
  }
}

// ---------------- GEMM1: H = w * relu(gather(x) @ W1[e] + b1[e]) ----------------
// R5 == R4 structure (BN=256, wave tile 64x128, all-gload_lds 3-deep pipeline,
// counted vmcnt(6), 1 barrier/round, chunk swizzle) -- R4's gemm1 was verified
// correct by enumeration; the R4 correctness bug was gemm2p-only (see below).
__global__ __launch_bounds__(256, 2) void k_gemm1(
    const half_t* __restrict__ xh, const half_t* __restrict__ w1t,
    const float* __restrict__ b1,
    const int* __restrict__ rowl, const float* __restrict__ wl,
    const int* __restrict__ cnt, const int* __restrict__ pbase,
    const int* __restrict__ i16b, const int* __restrict__ i16m,
    const int* __restrict__ n16, half_t* __restrict__ Hbuf)
{
  const int wi = blockIdx.y;
  if (wi >= *n16) return;
  const int bucket = i16b[wi];
  const int m0 = i16m[wi];
  const int count = cnt[bucket];
  const int e = bucket & 7;
  const int n0 = blockIdx.x * 256;
  const int t = threadIdx.x;

  __shared__ __align__(16) half_t As[3][128 * 32];   // 3 x 8KB
  __shared__ __align__(16) half_t Bs[3][256 * 32];   // 3 x 16KB
  __shared__ int rows_s[128];
  __shared__ float ws_s[128];

  if (t < 128) {
    int mi = m0 + t;
    int idx = bucket * NB + (mi < count ? mi : m0);
    rows_s[t] = rowl[idx];
    ws_s[t] = wl[idx];
  }
  __syncthreads();

  const int w = t >> 6, lane = t & 63;
  // A staging: 2 slots/wave (A tile 128x32 = 8 wave-loads)
  const int cA0 = (w * 2) * 64 + lane, cA1 = cA0 + 64;
  const int rA0 = cA0 >> 2, rA1 = cA1 >> 2;
  const int kA0 = ((cA0 & 3) ^ ((rA0 >> 1) & 3)) * 8;
  const int kA1 = ((cA1 & 3) ^ ((rA1 >> 1) & 3)) * 8;
  const half_t* gA0 = xh + (size_t)rows_s[rA0] * ND + kA0;
  const half_t* gA1 = xh + (size_t)rows_s[rA1] * ND + kA1;
  // B staging: 4 slots/wave (B tile 256x32 = 16 wave-loads)
  const half_t* w1te = w1t + (size_t)e * NP * ND;
  const int cB0 = (w * 4) * 64 + lane, cB1 = cB0 + 64, cB2 = cB0 + 128, cB3 = cB0 + 192;
  const int rB0 = cB0 >> 2, rB1 = cB1 >> 2, rB2 = cB2 >> 2, rB3 = cB3 >> 2;
  const half_t* gB0 = w1te + (size_t)(n0 + rB0) * ND + ((cB0 & 3) ^ ((rB0 >> 1) & 3)) * 8;
  const half_t* gB1 = w1te + (size_t)(n0 + rB1) * ND + ((cB1 & 3) ^ ((rB1 >> 1) & 3)) * 8;
  const half_t* gB2 = w1te + (size_t)(n0 + rB2) * ND + ((cB2 & 3) ^ ((rB2 >> 1) & 3)) * 8;
  const half_t* gB3 = w1te + (size_t)(n0 + rB3) * ND + ((cB3 & 3) ^ ((rB3 >> 1) & 3)) * 8;

  const int wr = w >> 1, wc = w & 1;
  const int lrow = lane & 15, lk = lane >> 4;
  const int lko = (lk ^ ((lrow >> 1) & 3)) * 8;

  f32x4 acc[4][8];
#pragma unroll
  for (int i = 0; i < 4; i++)
#pragma unroll
    for (int j = 0; j < 8; j++) {
      acc[i][j][0] = 0.f; acc[i][j][1] = 0.f; acc[i][j][2] = 0.f; acc[i][j][3] = 0.f;
    }

  auto stage = [&](int bi, int tt) {
    const int kk = tt * 32;
    half_t* la = &As[bi][w * 1024];
    gload16(gA0 + kk, la);
    gload16(gA1 + kk, la + 512);
    half_t* lb = &Bs[bi][w * 2048];
    gload16(gB0 + kk, lb);
    gload16(gB1 + kk, lb + 512);
    gload16(gB2 + kk, lb + 1024);
    gload16(gB3 + kk, lb + 1536);
  };
  auto compute = [&](int bi) {
    f16x8 af[4], bf[8];
#pragma unroll
    for (int i = 0; i < 4; i++)
      af[i] = *reinterpret_cast<const f16x8*>(&As[bi][(wr * 64 + i * 16 + lrow) * 32 + lko]);
#pragma unroll
    for (int n = 0; n < 8; n++)
      bf[n] = *reinterpret_cast<const f16x8*>(&Bs[bi][(wc * 128 + n * 16 + lrow) * 32 + lko]);
#pragma unroll
    for (int mi = 0; mi < 4; mi++)
#pragma unroll
      for (int ni = 0; ni < 8; ni++)
        acc[mi][ni] = __builtin_amdgcn_mfma_f32_16x16x32_f16(af[mi], bf[ni], acc[mi][ni], 0, 0, 0);
  };

  // 64 rounds. 6 loads/wave/stage -> steady wait = vmcnt(6) (next tile landed,
  // tile after stays in flight across the barrier).
  stage(0, 0);
  stage(1, 1);
  asm volatile("s_waitcnt vmcnt(6)" ::: "memory");
  __builtin_amdgcn_s_barrier();
  for (int t3 = 0; t3 < 60; t3 += 3) {
    stage(2, t3 + 2); compute(0);
    asm volatile("s_waitcnt vmcnt(6) lgkmcnt(0)" ::: "memory");
    __builtin_amdgcn_s_barrier();
    stage(0, t3 + 3); compute(1);
    asm volatile("s_waitcnt vmcnt(6) lgkmcnt(0)" ::: "memory");
    __builtin_amdgcn_s_barrier();
    stage(1, t3 + 4); compute(2);
    asm volatile("s_waitcnt vmcnt(6) lgkmcnt(0)" ::: "memory");
    __builtin_amdgcn_s_barrier();
  }
  // rounds 60..63
  stage(2, 62); compute(0);
  asm volatile("s_waitcnt vmcnt(6) lgkmcnt(0)" ::: "memory");
  __builtin_amdgcn_s_barrier();
  stage(0, 63); compute(1);
  asm volatile("s_waitcnt vmcnt(6) lgkmcnt(0)" ::: "memory");
  __builtin_amdgcn_s_barrier();
  compute(2);
  asm volatile("s_waitcnt vmcnt(0) lgkmcnt(0)" ::: "memory");
  __builtin_amdgcn_s_barrier();
  compute(0);

  const int pb = pbase[bucket];
#pragma unroll
  for (int mi = 0; mi < 4; mi++) {
#pragma unroll
    for (int i = 0; i < 4; i++) {
      int lm = wr * 64 + mi * 16 + lk * 4 + i;
      if (m0 + lm < count) {
        size_t prow = (size_t)(pb + m0 + lm) * NP;
        float wcoef = ws_s[lm];
#pragma unroll
        for (int ni = 0; ni < 8; ni++) {
          int col = n0 + wc * 128 + ni * 16 + lrow;
          float v = acc[mi][ni][i] + b1[e * NP + col];
          v = v > 0.f ? v : 0.f;
          Hbuf[prow + col] = (half_t)(v * wcoef);  // pre-scale by gate weight
        }
      }
    }
  }
}

// ---- GEMM2 (pair-fused): out[r] = H0w@W2[e0] + H1w@W2[e1] + w0*b2[e0] + w1*b2[e1] ----
// R5 FIX: R4 had NT=16 / kk=(tt&7)*32 / seg=tt&8 -> only K=0..255 of the
// NP=512 H-rows entered the dot product (absmax 1.86). Correct iteration
// space is R2's: NT=32 rounds of BK=32, kk=(tt&15)*32, segment = tt&16.
__global__ __launch_bounds__(256, 2) void k_gemm2p(
    const half_t* __restrict__ Hbuf, const half_t* __restrict__ w2t,
    const float* __restrict__ b2,
    const int* __restrict__ rowlp, const int* __restrict__ cntp,
    const int* __restrict__ pbase,
    const int* __restrict__ pos0a, const int* __restrict__ pos1a,
    const float* __restrict__ w0a, const float* __restrict__ w1a,
    const int* __restrict__ ipp, const int* __restrict__ ipm,
    const int* __restrict__ np, float* __restrict__ out)
{
  const int wi = blockIdx.y;
  if (wi >= *np) return;
  const int p = ipp[wi];
  const int m0 = ipm[wi];
  const int count = cntp[p];
  const int e0 = p >> 3, e1 = p & 7;
  const int n0 = blockIdx.x * 256;
  const int t = threadIdx.x;

  __shared__ __align__(16) half_t As[3][128 * 32];
  __shared__ __align__(16) half_t Bs[3][256 * 32];
  __shared__ int h0_s[128], h1_s[128], rs_s[128];
  __shared__ float w0_s[128], w1_s[128];

  if (t < 128) {
    int mi = m0 + t;
    int r = rowlp[p * NB + (mi < count ? mi : m0)];
    rs_s[t] = r;
    h0_s[t] = pbase[e0] + pos0a[r];
    h1_s[t] = pbase[8 + e1] + pos1a[r];
    w0_s[t] = w0a[r];
    w1_s[t] = w1a[r];
  }
  __syncthreads();

  const int w = t >> 6, lane = t & 63;
  const int cA0 = (w * 2) * 64 + lane, cA1 = cA0 + 64;
  const int rA0 = cA0 >> 2, rA1 = cA1 >> 2;
  const int kA0 = ((cA0 & 3) ^ ((rA0 >> 1) & 3)) * 8;
  const int kA1 = ((cA1 & 3) ^ ((rA1 >> 1) & 3)) * 8;
  const half_t* sa00 = Hbuf + (size_t)h0_s[rA0] * NP + kA0;
  const half_t* sa01 = Hbuf + (size_t)h0_s[rA1] * NP + kA1;
  const half_t* sa10 = Hbuf + (size_t)h1_s[rA0] * NP + kA0;
  const half_t* sa11 = Hbuf + (size_t)h1_s[rA1] * NP + kA1;

  const half_t* w2e0 = w2t + (size_t)e0 * ND * NP;
  const half_t* w2e1 = w2t + (size_t)e1 * ND * NP;
  const int cB0 = (w * 4) * 64 + lane, cB1 = cB0 + 64, cB2 = cB0 + 128, cB3 = cB0 + 192;
  const int rB0 = cB0 >> 2, rB1 = cB1 >> 2, rB2 = cB2 >> 2, rB3 = cB3 >> 2;
  const int kB0 = ((cB0 & 3) ^ ((rB0 >> 1) & 3)) * 8;
  const int kB1 = ((cB1 & 3) ^ ((rB1 >> 1) & 3)) * 8;
  const int kB2 = ((cB2 & 3) ^ ((rB2 >> 1) & 3)) * 8;
  const int kB3 = ((cB3 & 3) ^ ((rB3 >> 1) & 3)) * 8;
  const half_t* pB00 = w2e0 + (size_t)(n0 + rB0) * NP + kB0;
  const half_t* pB01 = w2e0 + (size_t)(n0 + rB1) * NP + kB1;
  const half_t* pB02 = w2e0 + (size_t)(n0 + rB2) * NP + kB2;
  const half_t* pB03 = w2e0 + (size_t)(n0 + rB3) * NP + kB3;
  const half_t* pB10 = w2e1 + (size_t)(n0 + rB0) * NP + kB0;
  const half_t* pB11 = w2e1 + (size_t)(n0 + rB1) * NP + kB1;
  const half_t* pB12 = w2e1 + (size_t)(n0 + rB2) * NP + kB2;
  const half_t* pB13 = w2e1 + (size_t)(n0 + rB3) * NP + kB3;

  const int wr = w >> 1, wc = w & 1;
  const int lrow = lane & 15, lk = lane >> 4;
  const int lko = (lk ^ ((lrow >> 1) & 3)) * 8;

  f32x4 acc[4][8];
#pragma unroll
  for (int i = 0; i < 4; i++)
#pragma unroll
    for (int j = 0; j < 8; j++) {
      acc[i][j][0] = 0.f; acc[i][j][1] = 0.f; acc[i][j][2] = 0.f; acc[i][j][3] = 0.f;
    }

  const int NT = 32;  // 2 segments x 16 rounds of BK=32 (full NP=512 each)

  auto stage = [&](int bi, int tt) {
    const int kk = (tt & 15) * 32;
    half_t* la = &As[bi][w * 1024];
    half_t* lb = &Bs[bi][w * 2048];
    if (tt & 16) {
      gload16(sa10 + kk, la);
      gload16(sa11 + kk, la + 512);
      gload16(pB10 + kk, lb);
      gload16(pB11 + kk, lb + 512);
      gload16(pB12 + kk, lb + 1024);
      gload16(pB13 + kk, lb + 1536);
    } else {
      gload16(sa00 + kk, la);
      gload16(sa01 + kk, la + 512);
      gload16(pB00 + kk, lb);
      gload16(pB01 + kk, lb + 512);
      gload16(pB02 + kk, lb + 1024);
      gload16(pB03 + kk, lb + 1536);
    }
  };
  auto compute = [&](int bi) {
    f16x8 af[4], bf[8];
#pragma unroll
    for (int i = 0; i < 4; i++)
      af[i] = *reinterpret_cast<const f16x8*>(&As[bi][(wr * 64 + i * 16 + lrow) * 32 + lko]);
#pragma unroll
    for (int n = 0; n < 8; n++)
      bf[n] = *reinterpret_cast<const f16x8*>(&Bs[bi][(wc * 128 + n * 16 + lrow) * 32 + lko]);
#pragma unroll
    for (int mi = 0; mi < 4; mi++)
#pragma unroll
      for (int ni = 0; ni < 8; ni++)
        acc[mi][ni] = __builtin_amdgcn_mfma_f32_16x16x32_f16(af[mi], bf[ni], acc[mi][ni], 0, 0, 0);
  };

  stage(0, 0);
  stage(1, 1);
  asm volatile("s_waitcnt vmcnt(6)" ::: "memory");
  __builtin_amdgcn_s_barrier();
#pragma unroll
  for (int tt = 0; tt < NT; ++tt) {
    if (tt + 2 < NT) stage((tt + 2) % 3, tt + 2);
    compute(tt % 3);
    if (tt + 1 < NT) {
      if (tt + 2 < NT) asm volatile("s_waitcnt vmcnt(6) lgkmcnt(0)" ::: "memory");
      else             asm volatile("s_waitcnt vmcnt(0) lgkmcnt(0)" ::: "memory");
      __builtin_amdgcn_s_barrier();
    }
  }

  // epilogue: single write of the combined row
  float b20[8], b21[8];
#pragma unroll
  for (int ni = 0; ni < 8; ni++) {
    int col = n0 + wc * 128 + ni * 16 + lrow;
    b20[ni] = b2[e0 * ND + col];
    b21[ni] = b2[e1 * ND + col];
  }
#pragma unroll
  for (int mi = 0; mi < 4; mi++) {
#pragma unroll
    for (int i = 0; i < 4; i++) {
      int lm = wr * 64 + mi * 16 + lk * 4 + i;
      if (m0 + lm < count) {
        int r = rs_s[lm];
        float wb0 = w0_s[lm], wb1 = w1_s[lm];
        float* orow = out + (size_t)r * ND;
#pragma unroll
        for (int ni = 0; ni < 8; ni++) {
          int col = n0 + wc * 128 + ni * 16 + lrow;
          orow[col] = acc[mi][ni][i] + wb0 * b20[ni] + wb1 * b21[ni];
        }
      }
    }
  }
}

extern "C" void kernel_launch(void* const* d_in, const int* in_sizes, int n_in,
                              void* d_out, int out_size, void* d_ws, size_t ws_size,
                              hipStream_t stream)
{
  const float* x   = (const float*)d_in[0];
  const float* Wg  = (const float*)d_in[1];
  const float* bg  = (const float*)d_in[2];
  const float* Wp  = (const float*)d_in[3];
  const float* bp  = (const float*)d_in[4];
  const float* Wgg = (const float*)d_in[5];
  const float* bgg = (const float*)d_in[6];
  const float* W1  = (const float*)d_in[7];
  const float* b1  = (const float*)d_in[8];
  const float* W2  = (const float*)d_in[9];
  const float* b2  = (const float*)d_in[10];
  float* out = (float*)d_out;

  char* ws = (char*)d_ws;
  size_t off = 0;
  const size_t OFF_XH   = off; off += (size_t)NB * ND * 2;              // 32 MB
  const size_t OFF_W1T  = off; off += (size_t)NE * NP * ND * 2;         // 16 MB
  const size_t OFF_W2T  = off; off += (size_t)NE * ND * NP * 2;         // 16 MB
  const size_t OFF_H    = off; off += (size_t)(2 * NB + 128) * NP * 2;  // ~17 MB
  const size_t OFF_ROWL = off; off += (size_t)16 * NB * 4;
  const size_t OFF_WL   = off; off += (size_t)16 * NB * 4;
  const size_t OFF_ROWLP= off; off += (size_t)64 * NB * 4;              // 2 MB
  const size_t OFF_CNT  = off; off += 64;
  const size_t OFF_CNTP = off; off += 256;
  const size_t OFF_PB   = off; off += 64;
  const size_t OFF_QM   = off; off += (size_t)NB * 8;
  const size_t OFF_E0   = off; off += (size_t)NB * 4;
  const size_t OFF_E1   = off; off += (size_t)NB * 4;
  const size_t OFF_W0   = off; off += (size_t)NB * 4;
  const size_t OFF_W1A  = off; off += (size_t)NB * 4;
  const size_t OFF_POS0 = off; off += (size_t)NB * 4;
  const size_t OFF_POS1 = off; off += (size_t)NB * 4;
  const size_t OFF_I16B = off; off += 1024;
  const size_t OFF_I16M = off; off += 1024;
  const size_t OFF_N16  = off; off += 64;
  const size_t OFF_IPP  = off; off += 1024;
  const size_t OFF_IPM  = off; off += 1024;
  const size_t OFF_NP   = off; off += 64;

  half_t* xh   = (half_t*)(ws + OFF_XH);
  half_t* w1t  = (half_t*)(ws + OFF_W1T);
  half_t* w2t  = (half_t*)(ws + OFF_W2T);
  half_t* Hbuf = (half_t*)(ws + OFF_H);
  int*    rowl = (int*)(ws + OFF_ROWL);
  float*  wl   = (float*)(ws + OFF_WL);
  int*    rowlp= (int*)(ws + OFF_ROWLP);
  int*    cnt  = (int*)(ws + OFF_CNT);
  int*    cntp = (int*)(ws + OFF_CNTP);
  int*    pb   = (int*)(ws + OFF_PB);
  double* qm   = (double*)(ws + OFF_QM);
  int*    e0a  = (int*)(ws + OFF_E0);
  int*    e1a  = (int*)(ws + OFF_E1);
  float*  w0a  = (float*)(ws + OFF_W0);
  float*  w1a  = (float*)(ws + OFF_W1A);
  int*    pos0a= (int*)(ws + OFF_POS0);
  int*    pos1a= (int*)(ws + OFF_POS1);
  int*    i16b = (int*)(ws + OFF_I16B);
  int*    i16m = (int*)(ws + OFF_I16M);
  int*    n16  = (int*)(ws + OFF_N16);
  int*    ipp  = (int*)(ws + OFF_IPP);
  int*    ipm  = (int*)(ws + OFF_IPM);
  int*    np   = (int*)(ws + OFF_NP);

  hipMemsetAsync(cnt, 0, 64 + 256, stream);  // cnt + cntp are contiguous
  k_convert<<<NB, 256, 0, stream>>>(x, xh, qm);
  k_cvt_w<<<dim3(8192, 2, 1), 256, 0, stream>>>(W1, W2, w1t, w2t);
  k_gate<<<NB / 4, 256, 0, stream>>>(qm, Wg, bg, Wp, bp, Wgg, bgg, e0a, e1a, w0a, w1a);
  k_bucket<<<NB / 256, 256, 0, stream>>>(e0a, e1a, w0a, w1a, rowl, wl, cnt,
                                         pos0a, pos1a, rowlp, cntp);
  k_prefix<<<1, 64, 0, stream>>>(cnt, cntp, pb, i16b, i16m, n16, ipp, ipm, np);
  // n16 worst case: 16384/128 + 16 partial tiles = 144; BN=256 -> grid.x = 2
  k_gemm1<<<dim3(2, 144, 1), 256, 0, stream>>>(xh, w1t, b1, rowl, wl, cnt, pb,
                                               i16b, i16m, n16, Hbuf);
  // np worst case: 8192/128 + 64 partial tiles = 128; BN=256 -> grid.x = 8
  k_gemm2p<<<dim3(8, 128, 1), 256, 0, stream>>>(Hbuf, w2t, b2, rowlp, cntp, pb,
                                                 pos0a, pos1a, w0a, w1a, ipp, ipm, np, out);
}

// Round 6
// 342.980 us; speedup vs baseline: 1.2272x; 1.0518x over previous
//
#include <hip/hip_runtime.h>
#include <stdint.h>

#define NB 8192
#define ND 2048
#define NE 8
#define NG 4
#define NP 512
#define NH 192

typedef _Float16 half_t;
typedef half_t f16x8 __attribute__((ext_vector_type(8)));
typedef float f32x4 __attribute__((ext_vector_type(4)));

__device__ __forceinline__ void gload16(const void* g, void* l) {
  __builtin_amdgcn_global_load_lds(
      (const __attribute__((address_space(1))) void*)g,
      (__attribute__((address_space(3))) void*)l, 16, 0, 0);
}

// ---------------- x -> fp16 conversion + fp64 row mean ----------------
__global__ __launch_bounds__(256) void k_convert(
    const float* __restrict__ x, half_t* __restrict__ xh, double* __restrict__ qm)
{
  const int b = blockIdx.x;
  const int t = threadIdx.x;
  const float* xr = x + (size_t)b * ND;
  const float4 v0 = ((const float4*)xr)[t * 2];
  const float4 v1 = ((const float4*)xr)[t * 2 + 1];
  float f[8] = {v0.x, v0.y, v0.z, v0.w, v1.x, v1.y, v1.z, v1.w};
  double s = 0.0;
  __align__(16) half_t hb[8];
#pragma unroll
  for (int i = 0; i < 8; i++) { s += (double)f[i]; hb[i] = (half_t)f[i]; }
  *reinterpret_cast<int4*>(xh + (size_t)b * ND + t * 8) = *reinterpret_cast<const int4*>(hb);

#pragma unroll
  for (int m = 32; m >= 1; m >>= 1) s += __shfl_xor(s, m);
  __shared__ double part[4];
  if ((t & 63) == 0) part[t >> 6] = s;
  __syncthreads();
  if (t == 0) qm[b] = (part[0] + part[1] + part[2] + part[3]) / (double)ND;
}

// ---------------- gating: one wave per row, NO atomics ----------------
__global__ __launch_bounds__(256) void k_gate(
    const double* __restrict__ qm,
    const float* __restrict__ Wg, const float* __restrict__ bg,
    const float* __restrict__ Wp, const float* __restrict__ bp,
    const float* __restrict__ Wgg, const float* __restrict__ bgg,
    int* __restrict__ e0a, int* __restrict__ e1a,
    float* __restrict__ w0a, float* __restrict__ w1a)
{
  const int wave = threadIdx.x >> 6;
  const int lane = threadIdx.x & 63;
  const int b = blockIdx.x * 4 + wave;
  const double q = qm[b];

  double part = 0.0;
#pragma unroll
  for (int i = 0; i < 3; i++) {
    int h = lane + i * 64;  // 0..191
    double ang = q * (7.0 * (double)(h + 1));
    part += cos(ang) + sin(ang);
  }
#pragma unroll
  for (int m = 32; m >= 1; m >>= 1) part += __shfl_xor(part, m);
  const double tm = part / (2.0 * (double)NH);
  const double gi1 = 32.0 / 2048.0;  // mean spike rate is a constant (R0 analysis)

  double lg = -1.0e300;
  if (lane < 8) {
    const int e = lane, g = e & 3;
    lg = tm * (double)Wg[e] + gi1 * (double)Wg[NE + e] + (double)bg[e];
    lg -= 0.1 * (tm * (double)Wp[e] + gi1 * (double)Wp[NE + e] + (double)bp[e]);
    lg += tm * (double)Wgg[g] + gi1 * (double)Wgg[NG + g] + (double)bgg[g];
  }
  double mx = lg;
#pragma unroll
  for (int m = 4; m >= 1; m >>= 1) mx = fmax(mx, __shfl_xor(mx, m));
  double pe = 0.0;
  if (lane < 8) pe = exp(lg - mx);
  double ps = pe;
#pragma unroll
  for (int m = 4; m >= 1; m >>= 1) ps += __shfl_xor(ps, m);

  double lgs[8], pes[8];
#pragma unroll
  for (int e = 0; e < 8; e++) { lgs[e] = __shfl(lg, e); pes[e] = __shfl(pe, e); }

  if (lane == 0) {
    int e0 = 0;
    for (int e = 1; e < NE; e++) if (lgs[e] > lgs[e0]) e0 = e;
    int e1 = (e0 == 0) ? 1 : 0;
    for (int e = 0; e < NE; e++) if (e != e0 && lgs[e] > lgs[e1]) e1 = e;
    const double p0 = pes[e0] / ps;
    const double p1 = pes[e1] / ps;
    const double den = p0 + p1 + 1e-9;
    e0a[b] = e0; e1a[b] = e1;
    w0a[b] = (float)(p0 / den);
    w1a[b] = (float)(p1 / den);
  }
}

// ---------------- bucket build: slot-expert buckets + pair buckets ----------------
__global__ __launch_bounds__(256) void k_bucket(
    const int* __restrict__ e0a, const int* __restrict__ e1a,
    const float* __restrict__ w0a, const float* __restrict__ w1a,
    int* __restrict__ rowl, float* __restrict__ wl, int* __restrict__ cnt,
    int* __restrict__ pos0a, int* __restrict__ pos1a,
    int* __restrict__ rowlp, int* __restrict__ cntp)
{
  const int t = threadIdx.x;
  const int r = blockIdx.x * 256 + t;
  __shared__ int hist[16], base[16], cursor[16];
  __shared__ int histp[64], basep[64], cursorp[64];
  if (t < 16) { hist[t] = 0; cursor[t] = 0; }
  if (t < 64) { histp[t] = 0; cursorp[t] = 0; }
  __syncthreads();

  const int e0 = e0a[r], e1 = e1a[r];
  const int p = e0 * 8 + e1;
  atomicAdd(&hist[e0], 1);
  atomicAdd(&hist[8 + e1], 1);
  atomicAdd(&histp[p], 1);
  __syncthreads();
  if (t < 16) base[t] = atomicAdd(&cnt[t], hist[t]);
  if (t < 64) basep[t] = atomicAdd(&cntp[t], histp[t]);
  __syncthreads();

  int p0 = atomicAdd(&cursor[e0], 1);
  int idx0 = base[e0] + p0;
  rowl[e0 * NB + idx0] = r;
  wl[e0 * NB + idx0] = w0a[r];
  pos0a[r] = idx0;

  int p1 = atomicAdd(&cursor[8 + e1], 1);
  int idx1 = base[8 + e1] + p1;
  rowl[(8 + e1) * NB + idx1] = r;
  wl[(8 + e1) * NB + idx1] = w1a[r];
  pos1a[r] = idx1;

  int pp = atomicAdd(&cursorp[p], 1);
  rowlp[p * NB + basep[p] + pp] = r;
}

// ---------------- weight transpose + fp16 convert ----------------
// R6: 64(k)x32(n) tiles. Old version stored 2-byte halfs in 64B row segments
// (half-rate writes on 32MB). Now: dst row n gets 64 k-halfs written as
// 8 threads x 16B = 128B fully-coalesced segments. LDS [64][33] pad ->
// load conflict-free; store-phase reads are 2-way (free).
__global__ __launch_bounds__(256) void k_cvt_w(
    const float* __restrict__ W1, const float* __restrict__ W2,
    half_t* __restrict__ w1t, half_t* __restrict__ w2t)
{
  const int which = blockIdx.y;
  const int R = which ? NP : ND;   // src rows (k-dim)
  const int C = which ? ND : NP;   // src cols (n-dim)
  const float* src = which ? W2 : W1;
  half_t* dst = which ? w2t : w1t;
  const int tiles_c = C >> 5;                 // n-tiles of 32
  const int tiles_per_e = (R >> 6) * tiles_c; // k-tiles of 64
  int id = blockIdx.x;
  int e = id / tiles_per_e;
  int rem = id - e * tiles_per_e;
  int tr = rem / tiles_c, tc = rem - tr * tiles_c;  // tr: k-tile, tc: n-tile
  __shared__ float tile[64][33];
  const int t = threadIdx.x;

  // load: 64 rows(k) x 32 cols(n); thread: col = t&31, rows (t>>5)+8i
  const int lc = t & 31, lr = t >> 5;
  const float* s = src + (size_t)e * R * C + (size_t)(tr * 64) * C + tc * 32;
#pragma unroll
  for (int i = 0; i < 8; i++)
    tile[lr + i * 8][lc] = s[(size_t)(lr + i * 8) * C + lc];
  __syncthreads();

  // store: dst row n = tc*32 + (t>>3), k-chunk (t&7)*8 .. +7 -> one 16B store
  const int n = t >> 3, kc = (t & 7) * 8;
  __align__(16) half_t hb[8];
#pragma unroll
  for (int j = 0; j < 8; j++) hb[j] = (half_t)tile[kc + j][n];
  half_t* d = dst + (size_t)e * R * C + (size_t)(tc * 32 + n) * R + tr * 64 + kc;
  *reinterpret_cast<int4*>(d) = *reinterpret_cast<const int4*>(hb);
}

// ---------------- prefix + compact work-item lists ----------------
// R6: hoist all counter loads into registers (unrolled independent loads,
// ~1 latency instead of ~80 serialized); bucket-list and pair-list on
// DIFFERENT waves so they run in parallel.
__global__ void k_prefix(const int* __restrict__ cnt, const int* __restrict__ cntp,
                         int* __restrict__ pbase,
                         int* __restrict__ i16b, int* __restrict__ i16m, int* __restrict__ n16,
                         int* __restrict__ ipp, int* __restrict__ ipm, int* __restrict__ np)
{
  const int t = threadIdx.x;
  if (t == 0) {
    int c[16];
#pragma unroll
    for (int i = 0; i < 16; i++) c[i] = cnt[i];
    int s = 0;
#pragma unroll
    for (int i = 0; i < 16; i++) { pbase[i] = s; s += c[i]; }
    int k = 0;
    for (int b = 0; b < 16; b++)
      for (int m0 = 0; m0 < c[b]; m0 += 128) { i16b[k] = b; i16m[k] = m0; k++; }
    *n16 = k;
  } else if (t == 64) {
    int c[64];
#pragma unroll
    for (int i = 0; i < 64; i++) c[i] = cntp[i];
    int k = 0;
    for (int p = 0; p < 64; p++)
      for (int m0 = 0; m0 < c[p]; m0 += 128) { ipp[k] = p; ipm[k] = m0; k++; }
    *np = k;
  }
}

// ---------------- GEMM1: H = w * relu(gather(x) @ W1[e] + b1[e]) ----------------
// R6 == R5 (verified): BN=256, wave tile 64x128, all-gload_lds 3-deep pipeline,
// counted vmcnt(6), 1 barrier/round, chunk swizzle. Deduced ~55-67us in R5
// (dropped out of top-5; fabric-saturated regime banked the BN=256 traffic cut).
__global__ __launch_bounds__(256, 2) void k_gemm1(
    const half_t* __restrict__ xh, const half_t* __restrict__ w1t,
    const float* __restrict__ b1,
    const int* __restrict__ rowl, const float* __restrict__ wl,
    const int* __restrict__ cnt, const int* __restrict__ pbase,
    const int* __restrict__ i16b, const int* __restrict__ i16m,
    const int* __restrict__ n16, half_t* __restrict__ Hbuf)
{
  const int wi = blockIdx.y;
  if (wi >= *n16) return;
  const int bucket = i16b[wi];
  const int m0 = i16m[wi];
  const int count = cnt[bucket];
  const int e = bucket & 7;
  const int n0 = blockIdx.x * 256;
  const int t = threadIdx.x;

  __shared__ __align__(16) half_t As[3][128 * 32];   // 3 x 8KB
  __shared__ __align__(16) half_t Bs[3][256 * 32];   // 3 x 16KB
  __shared__ int rows_s[128];
  __shared__ float ws_s[128];

  if (t < 128) {
    int mi = m0 + t;
    int idx = bucket * NB + (mi < count ? mi : m0);
    rows_s[t] = rowl[idx];
    ws_s[t] = wl[idx];
  }
  __syncthreads();

  const int w = t >> 6, lane = t & 63;
  const int cA0 = (w * 2) * 64 + lane, cA1 = cA0 + 64;
  const int rA0 = cA0 >> 2, rA1 = cA1 >> 2;
  const int kA0 = ((cA0 & 3) ^ ((rA0 >> 1) & 3)) * 8;
  const int kA1 = ((cA1 & 3) ^ ((rA1 >> 1) & 3)) * 8;
  const half_t* gA0 = xh + (size_t)rows_s[rA0] * ND + kA0;
  const half_t* gA1 = xh + (size_t)rows_s[rA1] * ND + kA1;
  const half_t* w1te = w1t + (size_t)e * NP * ND;
  const int cB0 = (w * 4) * 64 + lane, cB1 = cB0 + 64, cB2 = cB0 + 128, cB3 = cB0 + 192;
  const int rB0 = cB0 >> 2, rB1 = cB1 >> 2, rB2 = cB2 >> 2, rB3 = cB3 >> 2;
  const half_t* gB0 = w1te + (size_t)(n0 + rB0) * ND + ((cB0 & 3) ^ ((rB0 >> 1) & 3)) * 8;
  const half_t* gB1 = w1te + (size_t)(n0 + rB1) * ND + ((cB1 & 3) ^ ((rB1 >> 1) & 3)) * 8;
  const half_t* gB2 = w1te + (size_t)(n0 + rB2) * ND + ((cB2 & 3) ^ ((rB2 >> 1) & 3)) * 8;
  const half_t* gB3 = w1te + (size_t)(n0 + rB3) * ND + ((cB3 & 3) ^ ((rB3 >> 1) & 3)) * 8;

  const int wr = w >> 1, wc = w & 1;
  const int lrow = lane & 15, lk = lane >> 4;
  const int lko = (lk ^ ((lrow >> 1) & 3)) * 8;

  f32x4 acc[4][8];
#pragma unroll
  for (int i = 0; i < 4; i++)
#pragma unroll
    for (int j = 0; j < 8; j++) {
      acc[i][j][0] = 0.f; acc[i][j][1] = 0.f; acc[i][j][2] = 0.f; acc[i][j][3] = 0.f;
    }

  auto stage = [&](int bi, int tt) {
    const int kk = tt * 32;
    half_t* la = &As[bi][w * 1024];
    gload16(gA0 + kk, la);
    gload16(gA1 + kk, la + 512);
    half_t* lb = &Bs[bi][w * 2048];
    gload16(gB0 + kk, lb);
    gload16(gB1 + kk, lb + 512);
    gload16(gB2 + kk, lb + 1024);
    gload16(gB3 + kk, lb + 1536);
  };
  auto compute = [&](int bi) {
    f16x8 af[4], bf[8];
#pragma unroll
    for (int i = 0; i < 4; i++)
      af[i] = *reinterpret_cast<const f16x8*>(&As[bi][(wr * 64 + i * 16 + lrow) * 32 + lko]);
#pragma unroll
    for (int n = 0; n < 8; n++)
      bf[n] = *reinterpret_cast<const f16x8*>(&Bs[bi][(wc * 128 + n * 16 + lrow) * 32 + lko]);
#pragma unroll
    for (int mi = 0; mi < 4; mi++)
#pragma unroll
      for (int ni = 0; ni < 8; ni++)
        acc[mi][ni] = __builtin_amdgcn_mfma_f32_16x16x32_f16(af[mi], bf[ni], acc[mi][ni], 0, 0, 0);
  };

  stage(0, 0);
  stage(1, 1);
  asm volatile("s_waitcnt vmcnt(6)" ::: "memory");
  __builtin_amdgcn_s_barrier();
  for (int t3 = 0; t3 < 60; t3 += 3) {
    stage(2, t3 + 2); compute(0);
    asm volatile("s_waitcnt vmcnt(6) lgkmcnt(0)" ::: "memory");
    __builtin_amdgcn_s_barrier();
    stage(0, t3 + 3); compute(1);
    asm volatile("s_waitcnt vmcnt(6) lgkmcnt(0)" ::: "memory");
    __builtin_amdgcn_s_barrier();
    stage(1, t3 + 4); compute(2);
    asm volatile("s_waitcnt vmcnt(6) lgkmcnt(0)" ::: "memory");
    __builtin_amdgcn_s_barrier();
  }
  stage(2, 62); compute(0);
  asm volatile("s_waitcnt vmcnt(6) lgkmcnt(0)" ::: "memory");
  __builtin_amdgcn_s_barrier();
  stage(0, 63); compute(1);
  asm volatile("s_waitcnt vmcnt(6) lgkmcnt(0)" ::: "memory");
  __builtin_amdgcn_s_barrier();
  compute(2);
  asm volatile("s_waitcnt vmcnt(0) lgkmcnt(0)" ::: "memory");
  __builtin_amdgcn_s_barrier();
  compute(0);

  const int pb = pbase[bucket];
#pragma unroll
  for (int mi = 0; mi < 4; mi++) {
#pragma unroll
    for (int i = 0; i < 4; i++) {
      int lm = wr * 64 + mi * 16 + lk * 4 + i;
      if (m0 + lm < count) {
        size_t prow = (size_t)(pb + m0 + lm) * NP;
        float wcoef = ws_s[lm];
#pragma unroll
        for (int ni = 0; ni < 8; ni++) {
          int col = n0 + wc * 128 + ni * 16 + lrow;
          float v = acc[mi][ni][i] + b1[e * NP + col];
          v = v > 0.f ? v : 0.f;
          Hbuf[prow + col] = (half_t)(v * wcoef);  // pre-scale by gate weight
        }
      }
    }
  }
}

// ---- GEMM2 (pair-fused): out[r] = H0w@W2[e0] + H1w@W2[e1] + w0*b2[e0] + w1*b2[e1] ----
// R6: REVERT to R2's exact BN=128 version. R5's BN=256 variant dropped staging
// demand to 3.85 TB/s (not fabric-bound) but regressed 102us via block-count
// quantization / latency at 2 blocks/CU. R2 version: 3-buf, 4 loads/wave,
// vmcnt(4), NT=32 full unroll, 3 blocks/CU -- measured <=77us in R2.
__global__ __launch_bounds__(256) void k_gemm2p(
    const half_t* __restrict__ Hbuf, const half_t* __restrict__ w2t,
    const float* __restrict__ b2,
    const int* __restrict__ rowlp, const int* __restrict__ cntp,
    const int* __restrict__ pbase,
    const int* __restrict__ pos0a, const int* __restrict__ pos1a,
    const float* __restrict__ w0a, const float* __restrict__ w1a,
    const int* __restrict__ ipp, const int* __restrict__ ipm,
    const int* __restrict__ np, float* __restrict__ out)
{
  const int wi = blockIdx.y;
  if (wi >= *np) return;
  const int p = ipp[wi];
  const int m0 = ipm[wi];
  const int count = cntp[p];
  const int e0 = p >> 3, e1 = p & 7;
  const int n0 = blockIdx.x * 128;
  const int t = threadIdx.x;

  __shared__ __align__(16) half_t As[3][128 * 32];
  __shared__ __align__(16) half_t Bs[3][128 * 32];
  __shared__ int h0_s[128], h1_s[128], rs_s[128];
  __shared__ float w0_s[128], w1_s[128];

  if (t < 128) {
    int mi = m0 + t;
    int r = rowlp[p * NB + (mi < count ? mi : m0)];
    rs_s[t] = r;
    h0_s[t] = pbase[e0] + pos0a[r];
    h1_s[t] = pbase[8 + e1] + pos1a[r];
    w0_s[t] = w0a[r];
    w1_s[t] = w1a[r];
  }
  __syncthreads();

  const int w = t >> 6, lane = t & 63;
  const int c0 = w * 128 + lane, c1 = c0 + 64;
  const int row0 = c0 >> 2, ch0 = c0 & 3;
  const int row1 = c1 >> 2, ch1 = c1 & 3;
  const int sw0 = (row0 >> 1) & 3, sw1 = (row1 >> 1) & 3;
  const half_t* w2e0 = w2t + (size_t)e0 * ND * NP;
  const half_t* w2e1 = w2t + (size_t)e1 * ND * NP;
  const half_t* sa00 = Hbuf + (size_t)h0_s[row0] * NP + ((ch0 ^ sw0) * 8);
  const half_t* sa01 = Hbuf + (size_t)h0_s[row1] * NP + ((ch1 ^ sw1) * 8);
  const half_t* sa10 = Hbuf + (size_t)h1_s[row0] * NP + ((ch0 ^ sw0) * 8);
  const half_t* sa11 = Hbuf + (size_t)h1_s[row1] * NP + ((ch1 ^ sw1) * 8);
  const half_t* pB00 = w2e0 + (size_t)(n0 + row0) * NP + ((ch0 ^ sw0) * 8);
  const half_t* pB01 = w2e0 + (size_t)(n0 + row1) * NP + ((ch1 ^ sw1) * 8);
  const half_t* pB10 = w2e1 + (size_t)(n0 + row0) * NP + ((ch0 ^ sw0) * 8);
  const half_t* pB11 = w2e1 + (size_t)(n0 + row1) * NP + ((ch1 ^ sw1) * 8);

  const int wr = w >> 1, wc = w & 1;
  const int lrow = lane & 15, lk = lane >> 4;
  const int lko = (lk ^ ((lrow >> 1) & 3)) * 8;

  f32x4 acc[4][4];
#pragma unroll
  for (int i = 0; i < 4; i++)
#pragma unroll
    for (int j = 0; j < 4; j++) {
      acc[i][j][0] = 0.f; acc[i][j][1] = 0.f; acc[i][j][2] = 0.f; acc[i][j][3] = 0.f;
    }

  const int NT = 32;  // 2 segments x 16 rounds of BK=32 (full NP=512 each)

  auto stage = [&](int bi, int tt) {
    const int kk = (tt & 15) * 32;
    half_t* la = &As[bi][w * 1024];
    half_t* lb = &Bs[bi][w * 1024];
    if (tt & 16) {
      gload16(sa10 + kk, la);
      gload16(sa11 + kk, la + 512);
      gload16(pB10 + kk, lb);
      gload16(pB11 + kk, lb + 512);
    } else {
      gload16(sa00 + kk, la);
      gload16(sa01 + kk, la + 512);
      gload16(pB00 + kk, lb);
      gload16(pB01 + kk, lb + 512);
    }
  };
  auto compute = [&](int bi) {
    f16x8 af[4], bf[4];
#pragma unroll
    for (int i = 0; i < 4; i++) {
      af[i] = *reinterpret_cast<const f16x8*>(&As[bi][(wr * 64 + i * 16 + lrow) * 32 + lko]);
      bf[i] = *reinterpret_cast<const f16x8*>(&Bs[bi][(wc * 64 + i * 16 + lrow) * 32 + lko]);
    }
#pragma unroll
    for (int mi = 0; mi < 4; mi++)
#pragma unroll
      for (int ni = 0; ni < 4; ni++)
        acc[mi][ni] = __builtin_amdgcn_mfma_f32_16x16x32_f16(af[mi], bf[ni], acc[mi][ni], 0, 0, 0);
  };

  stage(0, 0);
  stage(1, 1);
  asm volatile("s_waitcnt vmcnt(4)" ::: "memory");
  __builtin_amdgcn_s_barrier();
#pragma unroll
  for (int tt = 0; tt < NT; ++tt) {
    if (tt + 2 < NT) stage((tt + 2) % 3, tt + 2);
    compute(tt % 3);
    if (tt + 1 < NT) {
      if (tt + 2 < NT) asm volatile("s_waitcnt vmcnt(4) lgkmcnt(0)" ::: "memory");
      else             asm volatile("s_waitcnt vmcnt(0) lgkmcnt(0)" ::: "memory");
      __builtin_amdgcn_s_barrier();
    }
  }

  // epilogue: single write of the combined row
  float b20[4], b21[4];
#pragma unroll
  for (int ni = 0; ni < 4; ni++) {
    int col = n0 + wc * 64 + ni * 16 + lrow;
    b20[ni] = b2[e0 * ND + col];
    b21[ni] = b2[e1 * ND + col];
  }
#pragma unroll
  for (int mi = 0; mi < 4; mi++) {
#pragma unroll
    for (int i = 0; i < 4; i++) {
      int lm = wr * 64 + mi * 16 + lk * 4 + i;
      if (m0 + lm < count) {
        int r = rs_s[lm];
        float wb0 = w0_s[lm], wb1 = w1_s[lm];
        float* orow = out + (size_t)r * ND;
#pragma unroll
        for (int ni = 0; ni < 4; ni++) {
          int col = n0 + wc * 64 + ni * 16 + lrow;
          orow[col] = acc[mi][ni][i] + wb0 * b20[ni] + wb1 * b21[ni];
        }
      }
    }
  }
}

extern "C" void kernel_launch(void* const* d_in, const int* in_sizes, int n_in,
                              void* d_out, int out_size, void* d_ws, size_t ws_size,
                              hipStream_t stream)
{
  const float* x   = (const float*)d_in[0];
  const float* Wg  = (const float*)d_in[1];
  const float* bg  = (const float*)d_in[2];
  const float* Wp  = (const float*)d_in[3];
  const float* bp  = (const float*)d_in[4];
  const float* Wgg = (const float*)d_in[5];
  const float* bgg = (const float*)d_in[6];
  const float* W1  = (const float*)d_in[7];
  const float* b1  = (const float*)d_in[8];
  const float* W2  = (const float*)d_in[9];
  const float* b2  = (const float*)d_in[10];
  float* out = (float*)d_out;

  char* ws = (char*)d_ws;
  size_t off = 0;
  const size_t OFF_XH   = off; off += (size_t)NB * ND * 2;              // 32 MB
  const size_t OFF_W1T  = off; off += (size_t)NE * NP * ND * 2;         // 16 MB
  const size_t OFF_W2T  = off; off += (size_t)NE * ND * NP * 2;         // 16 MB
  const size_t OFF_H    = off; off += (size_t)(2 * NB + 128) * NP * 2;  // ~17 MB
  const size_t OFF_ROWL = off; off += (size_t)16 * NB * 4;
  const size_t OFF_WL   = off; off += (size_t)16 * NB * 4;
  const size_t OFF_ROWLP= off; off += (size_t)64 * NB * 4;              // 2 MB
  const size_t OFF_CNT  = off; off += 64;
  const size_t OFF_CNTP = off; off += 256;
  const size_t OFF_PB   = off; off += 64;
  const size_t OFF_QM   = off; off += (size_t)NB * 8;
  const size_t OFF_E0   = off; off += (size_t)NB * 4;
  const size_t OFF_E1   = off; off += (size_t)NB * 4;
  const size_t OFF_W0   = off; off += (size_t)NB * 4;
  const size_t OFF_W1A  = off; off += (size_t)NB * 4;
  const size_t OFF_POS0 = off; off += (size_t)NB * 4;
  const size_t OFF_POS1 = off; off += (size_t)NB * 4;
  const size_t OFF_I16B = off; off += 1024;
  const size_t OFF_I16M = off; off += 1024;
  const size_t OFF_N16  = off; off += 64;
  const size_t OFF_IPP  = off; off += 1024;
  const size_t OFF_IPM  = off; off += 1024;
  const size_t OFF_NP   = off; off += 64;

  half_t* xh   = (half_t*)(ws + OFF_XH);
  half_t* w1t  = (half_t*)(ws + OFF_W1T);
  half_t* w2t  = (half_t*)(ws + OFF_W2T);
  half_t* Hbuf = (half_t*)(ws + OFF_H);
  int*    rowl = (int*)(ws + OFF_ROWL);
  float*  wl   = (float*)(ws + OFF_WL);
  int*    rowlp= (int*)(ws + OFF_ROWLP);
  int*    cnt  = (int*)(ws + OFF_CNT);
  int*    cntp = (int*)(ws + OFF_CNTP);
  int*    pb   = (int*)(ws + OFF_PB);
  double* qm   = (double*)(ws + OFF_QM);
  int*    e0a  = (int*)(ws + OFF_E0);
  int*    e1a  = (int*)(ws + OFF_E1);
  float*  w0a  = (float*)(ws + OFF_W0);
  float*  w1a  = (float*)(ws + OFF_W1A);
  int*    pos0a= (int*)(ws + OFF_POS0);
  int*    pos1a= (int*)(ws + OFF_POS1);
  int*    i16b = (int*)(ws + OFF_I16B);
  int*    i16m = (int*)(ws + OFF_I16M);
  int*    n16  = (int*)(ws + OFF_N16);
  int*    ipp  = (int*)(ws + OFF_IPP);
  int*    ipm  = (int*)(ws + OFF_IPM);
  int*    np   = (int*)(ws + OFF_NP);

  hipMemsetAsync(cnt, 0, 64 + 256, stream);  // cnt + cntp are contiguous
  k_convert<<<NB, 256, 0, stream>>>(x, xh, qm);
  // 64k x 32n tiles: W1 (2048/64)*(512/32)*8 = 4096; W2 (512/64)*(2048/32)*8 = 4096
  k_cvt_w<<<dim3(4096, 2, 1), 256, 0, stream>>>(W1, W2, w1t, w2t);
  k_gate<<<NB / 4, 256, 0, stream>>>(qm, Wg, bg, Wp, bp, Wgg, bgg, e0a, e1a, w0a, w1a);
  k_bucket<<<NB / 256, 256, 0, stream>>>(e0a, e1a, w0a, w1a, rowl, wl, cnt,
                                         pos0a, pos1a, rowlp, cntp);
  k_prefix<<<1, 128, 0, stream>>>(cnt, cntp, pb, i16b, i16m, n16, ipp, ipm, np);
  // n16 worst case: 16384/128 + 16 partial tiles = 144; BN=256 -> grid.x = 2
  k_gemm1<<<dim3(2, 144, 1), 256, 0, stream>>>(xh, w1t, b1, rowl, wl, cnt, pb,
                                               i16b, i16m, n16, Hbuf);
  // np worst case: 8192/128 + 64 partial tiles = 128; BN=128 -> grid.x = 16
  k_gemm2p<<<dim3(16, 128, 1), 256, 0, stream>>>(Hbuf, w2t, b2, rowlp, cntp, pb,
                                                 pos0a, pos1a, w0a, w1a, ipp, ipm, np, out);
}

// Round 7
// 333.127 us; speedup vs baseline: 1.2635x; 1.0296x over previous
//
#include <hip/hip_runtime.h>
#include <stdint.h>

#define NB 8192
#define ND 2048
#define NE 8
#define NG 4
#define NP 512
#define NH 192

typedef _Float16 half_t;
typedef half_t f16x8 __attribute__((ext_vector_type(8)));
typedef float f32x4 __attribute__((ext_vector_type(4)));

__device__ __forceinline__ void gload16(const void* g, void* l) {
  __builtin_amdgcn_global_load_lds(
      (const __attribute__((address_space(1))) void*)g,
      (__attribute__((address_space(3))) void*)l, 16, 0, 0);
}

// ---------------- fused pre-pass ----------------
// R7: one launch does all independent pre-work.
//  blocks [0, NB):        x->fp16 convert + row mean + FULL gate for row b
//                         (gate was its own 2048-block kernel; its f64
//                         transcendental work now overlaps cvt_w's memory)
//  blocks [NB, NB+8192):  weight transpose+convert (R6's verified k_cvt_w)
__global__ __launch_bounds__(256) void k_pre(
    const float* __restrict__ x, half_t* __restrict__ xh,
    const float* __restrict__ W1, const float* __restrict__ W2,
    half_t* __restrict__ w1t, half_t* __restrict__ w2t,
    const float* __restrict__ Wg, const float* __restrict__ bg,
    const float* __restrict__ Wp, const float* __restrict__ bp,
    const float* __restrict__ Wgg, const float* __restrict__ bgg,
    int* __restrict__ e0a, int* __restrict__ e1a,
    float* __restrict__ w0a, float* __restrict__ w1a)
{
  const int t = threadIdx.x;

  if (blockIdx.x >= NB) {
    // ---------- cvt_w branch (identical math to R6 k_cvt_w) ----------
    int id = blockIdx.x - NB;
    const int which = id >> 12;  // [0,4096) -> W1, [4096,8192) -> W2
    id &= 4095;
    const int R = which ? NP : ND;
    const int C = which ? ND : NP;
    const float* src = which ? W2 : W1;
    half_t* dst = which ? w2t : w1t;
    const int tiles_c = C >> 5;
    const int tiles_per_e = (R >> 6) * tiles_c;
    int e = id / tiles_per_e;
    int rem = id - e * tiles_per_e;
    int tr = rem / tiles_c, tc = rem - tr * tiles_c;
    __shared__ float tile[64][33];
    const int lc = t & 31, lr = t >> 5;
    const float* s = src + (size_t)e * R * C + (size_t)(tr * 64) * C + tc * 32;
#pragma unroll
    for (int i = 0; i < 8; i++)
      tile[lr + i * 8][lc] = s[(size_t)(lr + i * 8) * C + lc];
    __syncthreads();
    const int n = t >> 3, kc = (t & 7) * 8;
    __align__(16) half_t hb[8];
#pragma unroll
    for (int j = 0; j < 8; j++) hb[j] = (half_t)tile[kc + j][n];
    half_t* d = dst + (size_t)e * R * C + (size_t)(tc * 32 + n) * R + tr * 64 + kc;
    *reinterpret_cast<int4*>(d) = *reinterpret_cast<const int4*>(hb);
    return;
  }

  // ---------- convert + gate branch ----------
  const int b = blockIdx.x;
  const float* xr = x + (size_t)b * ND;
  const float4 v0 = ((const float4*)xr)[t * 2];
  const float4 v1 = ((const float4*)xr)[t * 2 + 1];
  float f[8] = {v0.x, v0.y, v0.z, v0.w, v1.x, v1.y, v1.z, v1.w};
  double s = 0.0;
  __align__(16) half_t hb[8];
#pragma unroll
  for (int i = 0; i < 8; i++) { s += (double)f[i]; hb[i] = (half_t)f[i]; }
  *reinterpret_cast<int4*>(xh + (size_t)b * ND + t * 8) = *reinterpret_cast<const int4*>(hb);

#pragma unroll
  for (int m = 32; m >= 1; m >>= 1) s += __shfl_xor(s, m);
  __shared__ double part[4];
  __shared__ double qm_s;
  if ((t & 63) == 0) part[t >> 6] = s;
  __syncthreads();
  if (t == 0) qm_s = (part[0] + part[1] + part[2] + part[3]) / (double)ND;
  __syncthreads();

  // gate: 192 threads each compute one cos+sin term (was 3/lane on 1 wave)
  const double q = qm_s;
  double g = 0.0;
  if (t < 192) {
    double ang = q * (7.0 * (double)(t + 1));
    g = cos(ang) + sin(ang);
  }
#pragma unroll
  for (int m = 32; m >= 1; m >>= 1) g += __shfl_xor(g, m);
  __shared__ double gp[4];
  if ((t & 63) == 0) gp[t >> 6] = g;
  __syncthreads();

  if (t < 64) {
    const double tm = (gp[0] + gp[1] + gp[2] + gp[3]) / (2.0 * (double)NH);
    const double gi1 = 32.0 / 2048.0;  // mean spike rate is a constant (R0 analysis)
    double lg = -1.0e300;
    if (t < 8) {
      const int e = t, gg = e & 3;
      lg = tm * (double)Wg[e] + gi1 * (double)Wg[NE + e] + (double)bg[e];
      lg -= 0.1 * (tm * (double)Wp[e] + gi1 * (double)Wp[NE + e] + (double)bp[e]);
      lg += tm * (double)Wgg[gg] + gi1 * (double)Wgg[NG + gg] + (double)bgg[gg];
    }
    double mx = lg;
#pragma unroll
    for (int m = 4; m >= 1; m >>= 1) mx = fmax(mx, __shfl_xor(mx, m));
    double pe = 0.0;
    if (t < 8) pe = exp(lg - mx);
    double ps = pe;
#pragma unroll
    for (int m = 4; m >= 1; m >>= 1) ps += __shfl_xor(ps, m);

    double lgs[8], pes[8];
#pragma unroll
    for (int e = 0; e < 8; e++) { lgs[e] = __shfl(lg, e); pes[e] = __shfl(pe, e); }

    if (t == 0) {
      int e0 = 0;
      for (int e = 1; e < NE; e++) if (lgs[e] > lgs[e0]) e0 = e;
      int e1 = (e0 == 0) ? 1 : 0;
      for (int e = 0; e < NE; e++) if (e != e0 && lgs[e] > lgs[e1]) e1 = e;
      const double p0 = pes[e0] / ps;
      const double p1 = pes[e1] / ps;
      const double den = p0 + p1 + 1e-9;
      e0a[b] = e0; e1a[b] = e1;
      w0a[b] = (float)(p0 / den);
      w1a[b] = (float)(p1 / den);
    }
  }
}

// ---------------- bucket build + fused prefix (last-block ticket) ----------------
__global__ __launch_bounds__(256) void k_bucket(
    const int* __restrict__ e0a, const int* __restrict__ e1a,
    const float* __restrict__ w0a, const float* __restrict__ w1a,
    int* __restrict__ rowl, float* __restrict__ wl, int* __restrict__ cnt,
    int* __restrict__ pos0a, int* __restrict__ pos1a,
    int* __restrict__ rowlp, int* __restrict__ cntp,
    int* __restrict__ ticket, int* __restrict__ pbase,
    int* __restrict__ i16b, int* __restrict__ i16m, int* __restrict__ n16,
    int* __restrict__ ipp, int* __restrict__ ipm, int* __restrict__ np)
{
  const int t = threadIdx.x;
  const int r = blockIdx.x * 256 + t;
  __shared__ int hist[16], base[16], cursor[16];
  __shared__ int histp[64], basep[64], cursorp[64];
  __shared__ int lastf;
  if (t < 16) { hist[t] = 0; cursor[t] = 0; }
  if (t < 64) { histp[t] = 0; cursorp[t] = 0; }
  __syncthreads();

  const int e0 = e0a[r], e1 = e1a[r];
  const int p = e0 * 8 + e1;
  atomicAdd(&hist[e0], 1);
  atomicAdd(&hist[8 + e1], 1);
  atomicAdd(&histp[p], 1);
  __syncthreads();
  if (t < 16) base[t] = atomicAdd(&cnt[t], hist[t]);
  if (t < 64) basep[t] = atomicAdd(&cntp[t], histp[t]);
  __syncthreads();

  int p0 = atomicAdd(&cursor[e0], 1);
  int idx0 = base[e0] + p0;
  rowl[e0 * NB + idx0] = r;
  wl[e0 * NB + idx0] = w0a[r];
  pos0a[r] = idx0;

  int p1 = atomicAdd(&cursor[8 + e1], 1);
  int idx1 = base[8 + e1] + p1;
  rowl[(8 + e1) * NB + idx1] = r;
  wl[(8 + e1) * NB + idx1] = w1a[r];
  pos1a[r] = idx1;

  int pp = atomicAdd(&cursorp[p], 1);
  rowlp[p * NB + basep[p] + pp] = r;

  // ---- last finishing block runs the prefix (saves a dependent launch) ----
  __threadfence();
  __syncthreads();
  if (t == 0) lastf = (atomicAdd(ticket, 1) == (int)gridDim.x - 1);
  __syncthreads();
  if (lastf) {
    if (t == 0) {
      int c[16];
#pragma unroll
      for (int i = 0; i < 16; i++) c[i] = atomicAdd(&cnt[i], 0);  // coherent read
      int s = 0;
#pragma unroll
      for (int i = 0; i < 16; i++) { pbase[i] = s; s += c[i]; }
      int k = 0;
      for (int bb = 0; bb < 16; bb++)
        for (int m0 = 0; m0 < c[bb]; m0 += 128) { i16b[k] = bb; i16m[k] = m0; k++; }
      *n16 = k;
    } else if (t == 64) {
      int c[64];
#pragma unroll
      for (int i = 0; i < 64; i++) c[i] = atomicAdd(&cntp[i], 0);
      int k = 0;
      for (int pq = 0; pq < 64; pq++)
        for (int m0 = 0; m0 < c[pq]; m0 += 128) { ipp[k] = pq; ipm[k] = m0; k++; }
      *np = k;
    }
  }
}

// ---------------- GEMM1: H = w * relu(gather(x) @ W1[e] + b1[e]) ----------------
// R7 == R6 (verified, 74.5us): BN=256, wave tile 64x128, all-gload_lds 3-deep
// pipeline, counted vmcnt(6), 1 barrier/round, chunk swizzle.
__global__ __launch_bounds__(256, 2) void k_gemm1(
    const half_t* __restrict__ xh, const half_t* __restrict__ w1t,
    const float* __restrict__ b1,
    const int* __restrict__ rowl, const float* __restrict__ wl,
    const int* __restrict__ cnt, const int* __restrict__ pbase,
    const int* __restrict__ i16b, const int* __restrict__ i16m,
    const int* __restrict__ n16, half_t* __restrict__ Hbuf)
{
  const int wi = blockIdx.y;
  if (wi >= *n16) return;
  const int bucket = i16b[wi];
  const int m0 = i16m[wi];
  const int count = cnt[bucket];
  const int e = bucket & 7;
  const int n0 = blockIdx.x * 256;
  const int t = threadIdx.x;

  __shared__ __align__(16) half_t As[3][128 * 32];   // 3 x 8KB
  __shared__ __align__(16) half_t Bs[3][256 * 32];   // 3 x 16KB
  __shared__ int rows_s[128];
  __shared__ float ws_s[128];

  if (t < 128) {
    int mi = m0 + t;
    int idx = bucket * NB + (mi < count ? mi : m0);
    rows_s[t] = rowl[idx];
    ws_s[t] = wl[idx];
  }
  __syncthreads();

  const int w = t >> 6, lane = t & 63;
  const int cA0 = (w * 2) * 64 + lane, cA1 = cA0 + 64;
  const int rA0 = cA0 >> 2, rA1 = cA1 >> 2;
  const int kA0 = ((cA0 & 3) ^ ((rA0 >> 1) & 3)) * 8;
  const int kA1 = ((cA1 & 3) ^ ((rA1 >> 1) & 3)) * 8;
  const half_t* gA0 = xh + (size_t)rows_s[rA0] * ND + kA0;
  const half_t* gA1 = xh + (size_t)rows_s[rA1] * ND + kA1;
  const half_t* w1te = w1t + (size_t)e * NP * ND;
  const int cB0 = (w * 4) * 64 + lane, cB1 = cB0 + 64, cB2 = cB0 + 128, cB3 = cB0 + 192;
  const int rB0 = cB0 >> 2, rB1 = cB1 >> 2, rB2 = cB2 >> 2, rB3 = cB3 >> 2;
  const half_t* gB0 = w1te + (size_t)(n0 + rB0) * ND + ((cB0 & 3) ^ ((rB0 >> 1) & 3)) * 8;
  const half_t* gB1 = w1te + (size_t)(n0 + rB1) * ND + ((cB1 & 3) ^ ((rB1 >> 1) & 3)) * 8;
  const half_t* gB2 = w1te + (size_t)(n0 + rB2) * ND + ((cB2 & 3) ^ ((rB2 >> 1) & 3)) * 8;
  const half_t* gB3 = w1te + (size_t)(n0 + rB3) * ND + ((cB3 & 3) ^ ((rB3 >> 1) & 3)) * 8;

  const int wr = w >> 1, wc = w & 1;
  const int lrow = lane & 15, lk = lane >> 4;
  const int lko = (lk ^ ((lrow >> 1) & 3)) * 8;

  f32x4 acc[4][8];
#pragma unroll
  for (int i = 0; i < 4; i++)
#pragma unroll
    for (int j = 0; j < 8; j++) {
      acc[i][j][0] = 0.f; acc[i][j][1] = 0.f; acc[i][j][2] = 0.f; acc[i][j][3] = 0.f;
    }

  auto stage = [&](int bi, int tt) {
    const int kk = tt * 32;
    half_t* la = &As[bi][w * 1024];
    gload16(gA0 + kk, la);
    gload16(gA1 + kk, la + 512);
    half_t* lb = &Bs[bi][w * 2048];
    gload16(gB0 + kk, lb);
    gload16(gB1 + kk, lb + 512);
    gload16(gB2 + kk, lb + 1024);
    gload16(gB3 + kk, lb + 1536);
  };
  auto compute = [&](int bi) {
    f16x8 af[4], bf[8];
#pragma unroll
    for (int i = 0; i < 4; i++)
      af[i] = *reinterpret_cast<const f16x8*>(&As[bi][(wr * 64 + i * 16 + lrow) * 32 + lko]);
#pragma unroll
    for (int n = 0; n < 8; n++)
      bf[n] = *reinterpret_cast<const f16x8*>(&Bs[bi][(wc * 128 + n * 16 + lrow) * 32 + lko]);
#pragma unroll
    for (int mi = 0; mi < 4; mi++)
#pragma unroll
      for (int ni = 0; ni < 8; ni++)
        acc[mi][ni] = __builtin_amdgcn_mfma_f32_16x16x32_f16(af[mi], bf[ni], acc[mi][ni], 0, 0, 0);
  };

  stage(0, 0);
  stage(1, 1);
  asm volatile("s_waitcnt vmcnt(6)" ::: "memory");
  __builtin_amdgcn_s_barrier();
  for (int t3 = 0; t3 < 60; t3 += 3) {
    stage(2, t3 + 2); compute(0);
    asm volatile("s_waitcnt vmcnt(6) lgkmcnt(0)" ::: "memory");
    __builtin_amdgcn_s_barrier();
    stage(0, t3 + 3); compute(1);
    asm volatile("s_waitcnt vmcnt(6) lgkmcnt(0)" ::: "memory");
    __builtin_amdgcn_s_barrier();
    stage(1, t3 + 4); compute(2);
    asm volatile("s_waitcnt vmcnt(6) lgkmcnt(0)" ::: "memory");
    __builtin_amdgcn_s_barrier();
  }
  stage(2, 62); compute(0);
  asm volatile("s_waitcnt vmcnt(6) lgkmcnt(0)" ::: "memory");
  __builtin_amdgcn_s_barrier();
  stage(0, 63); compute(1);
  asm volatile("s_waitcnt vmcnt(6) lgkmcnt(0)" ::: "memory");
  __builtin_amdgcn_s_barrier();
  compute(2);
  asm volatile("s_waitcnt vmcnt(0) lgkmcnt(0)" ::: "memory");
  __builtin_amdgcn_s_barrier();
  compute(0);

  const int pb = pbase[bucket];
#pragma unroll
  for (int mi = 0; mi < 4; mi++) {
#pragma unroll
    for (int i = 0; i < 4; i++) {
      int lm = wr * 64 + mi * 16 + lk * 4 + i;
      if (m0 + lm < count) {
        size_t prow = (size_t)(pb + m0 + lm) * NP;
        float wcoef = ws_s[lm];
#pragma unroll
        for (int ni = 0; ni < 8; ni++) {
          int col = n0 + wc * 128 + ni * 16 + lrow;
          float v = acc[mi][ni][i] + b1[e * NP + col];
          v = v > 0.f ? v : 0.f;
          Hbuf[prow + col] = (half_t)(v * wcoef);  // pre-scale by gate weight
        }
      }
    }
  }
}

// ---- GEMM2 (pair-fused): out[r] = H0w@W2[e0] + H1w@W2[e1] + w0*b2[e0] + w1*b2[e1] ----
// R7 == R6 (verified, <74us): BN=128, R2 pipeline, NT=32 full unroll.
__global__ __launch_bounds__(256) void k_gemm2p(
    const half_t* __restrict__ Hbuf, const half_t* __restrict__ w2t,
    const float* __restrict__ b2,
    const int* __restrict__ rowlp, const int* __restrict__ cntp,
    const int* __restrict__ pbase,
    const int* __restrict__ pos0a, const int* __restrict__ pos1a,
    const float* __restrict__ w0a, const float* __restrict__ w1a,
    const int* __restrict__ ipp, const int* __restrict__ ipm,
    const int* __restrict__ np, float* __restrict__ out)
{
  const int wi = blockIdx.y;
  if (wi >= *np) return;
  const int p = ipp[wi];
  const int m0 = ipm[wi];
  const int count = cntp[p];
  const int e0 = p >> 3, e1 = p & 7;
  const int n0 = blockIdx.x * 128;
  const int t = threadIdx.x;

  __shared__ __align__(16) half_t As[3][128 * 32];
  __shared__ __align__(16) half_t Bs[3][128 * 32];
  __shared__ int h0_s[128], h1_s[128], rs_s[128];
  __shared__ float w0_s[128], w1_s[128];

  if (t < 128) {
    int mi = m0 + t;
    int r = rowlp[p * NB + (mi < count ? mi : m0)];
    rs_s[t] = r;
    h0_s[t] = pbase[e0] + pos0a[r];
    h1_s[t] = pbase[8 + e1] + pos1a[r];
    w0_s[t] = w0a[r];
    w1_s[t] = w1a[r];
  }
  __syncthreads();

  const int w = t >> 6, lane = t & 63;
  const int c0 = w * 128 + lane, c1 = c0 + 64;
  const int row0 = c0 >> 2, ch0 = c0 & 3;
  const int row1 = c1 >> 2, ch1 = c1 & 3;
  const int sw0 = (row0 >> 1) & 3, sw1 = (row1 >> 1) & 3;
  const half_t* w2e0 = w2t + (size_t)e0 * ND * NP;
  const half_t* w2e1 = w2t + (size_t)e1 * ND * NP;
  const half_t* sa00 = Hbuf + (size_t)h0_s[row0] * NP + ((ch0 ^ sw0) * 8);
  const half_t* sa01 = Hbuf + (size_t)h0_s[row1] * NP + ((ch1 ^ sw1) * 8);
  const half_t* sa10 = Hbuf + (size_t)h1_s[row0] * NP + ((ch0 ^ sw0) * 8);
  const half_t* sa11 = Hbuf + (size_t)h1_s[row1] * NP + ((ch1 ^ sw1) * 8);
  const half_t* pB00 = w2e0 + (size_t)(n0 + row0) * NP + ((ch0 ^ sw0) * 8);
  const half_t* pB01 = w2e0 + (size_t)(n0 + row1) * NP + ((ch1 ^ sw1) * 8);
  const half_t* pB10 = w2e1 + (size_t)(n0 + row0) * NP + ((ch0 ^ sw0) * 8);
  const half_t* pB11 = w2e1 + (size_t)(n0 + row1) * NP + ((ch1 ^ sw1) * 8);

  const int wr = w >> 1, wc = w & 1;
  const int lrow = lane & 15, lk = lane >> 4;
  const int lko = (lk ^ ((lrow >> 1) & 3)) * 8;

  f32x4 acc[4][4];
#pragma unroll
  for (int i = 0; i < 4; i++)
#pragma unroll
    for (int j = 0; j < 4; j++) {
      acc[i][j][0] = 0.f; acc[i][j][1] = 0.f; acc[i][j][2] = 0.f; acc[i][j][3] = 0.f;
    }

  const int NT = 32;  // 2 segments x 16 rounds of BK=32 (full NP=512 each)

  auto stage = [&](int bi, int tt) {
    const int kk = (tt & 15) * 32;
    half_t* la = &As[bi][w * 1024];
    half_t* lb = &Bs[bi][w * 1024];
    if (tt & 16) {
      gload16(sa10 + kk, la);
      gload16(sa11 + kk, la + 512);
      gload16(pB10 + kk, lb);
      gload16(pB11 + kk, lb + 512);
    } else {
      gload16(sa00 + kk, la);
      gload16(sa01 + kk, la + 512);
      gload16(pB00 + kk, lb);
      gload16(pB01 + kk, lb + 512);
    }
  };
  auto compute = [&](int bi) {
    f16x8 af[4], bf[4];
#pragma unroll
    for (int i = 0; i < 4; i++) {
      af[i] = *reinterpret_cast<const f16x8*>(&As[bi][(wr * 64 + i * 16 + lrow) * 32 + lko]);
      bf[i] = *reinterpret_cast<const f16x8*>(&Bs[bi][(wc * 64 + i * 16 + lrow) * 32 + lko]);
    }
#pragma unroll
    for (int mi = 0; mi < 4; mi++)
#pragma unroll
      for (int ni = 0; ni < 4; ni++)
        acc[mi][ni] = __builtin_amdgcn_mfma_f32_16x16x32_f16(af[mi], bf[ni], acc[mi][ni], 0, 0, 0);
  };

  stage(0, 0);
  stage(1, 1);
  asm volatile("s_waitcnt vmcnt(4)" ::: "memory");
  __builtin_amdgcn_s_barrier();
#pragma unroll
  for (int tt = 0; tt < NT; ++tt) {
    if (tt + 2 < NT) stage((tt + 2) % 3, tt + 2);
    compute(tt % 3);
    if (tt + 1 < NT) {
      if (tt + 2 < NT) asm volatile("s_waitcnt vmcnt(4) lgkmcnt(0)" ::: "memory");
      else             asm volatile("s_waitcnt vmcnt(0) lgkmcnt(0)" ::: "memory");
      __builtin_amdgcn_s_barrier();
    }
  }

  // epilogue: single write of the combined row
  float b20[4], b21[4];
#pragma unroll
  for (int ni = 0; ni < 4; ni++) {
    int col = n0 + wc * 64 + ni * 16 + lrow;
    b20[ni] = b2[e0 * ND + col];
    b21[ni] = b2[e1 * ND + col];
  }
#pragma unroll
  for (int mi = 0; mi < 4; mi++) {
#pragma unroll
    for (int i = 0; i < 4; i++) {
      int lm = wr * 64 + mi * 16 + lk * 4 + i;
      if (m0 + lm < count) {
        int r = rs_s[lm];
        float wb0 = w0_s[lm], wb1 = w1_s[lm];
        float* orow = out + (size_t)r * ND;
#pragma unroll
        for (int ni = 0; ni < 4; ni++) {
          int col = n0 + wc * 64 + ni * 16 + lrow;
          orow[col] = acc[mi][ni][i] + wb0 * b20[ni] + wb1 * b21[ni];
        }
      }
    }
  }
}

extern "C" void kernel_launch(void* const* d_in, const int* in_sizes, int n_in,
                              void* d_out, int out_size, void* d_ws, size_t ws_size,
                              hipStream_t stream)
{
  const float* x   = (const float*)d_in[0];
  const float* Wg  = (const float*)d_in[1];
  const float* bg  = (const float*)d_in[2];
  const float* Wp  = (const float*)d_in[3];
  const float* bp  = (const float*)d_in[4];
  const float* Wgg = (const float*)d_in[5];
  const float* bgg = (const float*)d_in[6];
  const float* W1  = (const float*)d_in[7];
  const float* b1  = (const float*)d_in[8];
  const float* W2  = (const float*)d_in[9];
  const float* b2  = (const float*)d_in[10];
  float* out = (float*)d_out;

  char* ws = (char*)d_ws;
  size_t off = 0;
  const size_t OFF_XH   = off; off += (size_t)NB * ND * 2;              // 32 MB
  const size_t OFF_W1T  = off; off += (size_t)NE * NP * ND * 2;         // 16 MB
  const size_t OFF_W2T  = off; off += (size_t)NE * ND * NP * 2;         // 16 MB
  const size_t OFF_H    = off; off += (size_t)(2 * NB + 128) * NP * 2;  // ~17 MB
  const size_t OFF_ROWL = off; off += (size_t)16 * NB * 4;
  const size_t OFF_WL   = off; off += (size_t)16 * NB * 4;
  const size_t OFF_ROWLP= off; off += (size_t)64 * NB * 4;              // 2 MB
  const size_t OFF_CNT  = off; off += 64;
  const size_t OFF_CNTP = off; off += 256;
  const size_t OFF_TKT  = off; off += 64;   // ticket (inside the memset range)
  const size_t OFF_PB   = off; off += 64;
  const size_t OFF_E0   = off; off += (size_t)NB * 4;
  const size_t OFF_E1   = off; off += (size_t)NB * 4;
  const size_t OFF_W0   = off; off += (size_t)NB * 4;
  const size_t OFF_W1A  = off; off += (size_t)NB * 4;
  const size_t OFF_POS0 = off; off += (size_t)NB * 4;
  const size_t OFF_POS1 = off; off += (size_t)NB * 4;
  const size_t OFF_I16B = off; off += 1024;
  const size_t OFF_I16M = off; off += 1024;
  const size_t OFF_N16  = off; off += 64;
  const size_t OFF_IPP  = off; off += 1024;
  const size_t OFF_IPM  = off; off += 1024;
  const size_t OFF_NP   = off; off += 64;

  half_t* xh   = (half_t*)(ws + OFF_XH);
  half_t* w1t  = (half_t*)(ws + OFF_W1T);
  half_t* w2t  = (half_t*)(ws + OFF_W2T);
  half_t* Hbuf = (half_t*)(ws + OFF_H);
  int*    rowl = (int*)(ws + OFF_ROWL);
  float*  wl   = (float*)(ws + OFF_WL);
  int*    rowlp= (int*)(ws + OFF_ROWLP);
  int*    cnt  = (int*)(ws + OFF_CNT);
  int*    cntp = (int*)(ws + OFF_CNTP);
  int*    tkt  = (int*)(ws + OFF_TKT);
  int*    pb   = (int*)(ws + OFF_PB);
  int*    e0a  = (int*)(ws + OFF_E0);
  int*    e1a  = (int*)(ws + OFF_E1);
  float*  w0a  = (float*)(ws + OFF_W0);
  float*  w1a  = (float*)(ws + OFF_W1A);
  int*    pos0a= (int*)(ws + OFF_POS0);
  int*    pos1a= (int*)(ws + OFF_POS1);
  int*    i16b = (int*)(ws + OFF_I16B);
  int*    i16m = (int*)(ws + OFF_I16M);
  int*    n16  = (int*)(ws + OFF_N16);
  int*    ipp  = (int*)(ws + OFF_IPP);
  int*    ipm  = (int*)(ws + OFF_IPM);
  int*    np   = (int*)(ws + OFF_NP);

  hipMemsetAsync(cnt, 0, 64 + 256 + 64, stream);  // cnt + cntp + ticket contiguous
  // fused pre-pass: convert+gate (blocks 0..8191) || weight cvt (8192..16383)
  k_pre<<<NB + 8192, 256, 0, stream>>>(x, xh, W1, W2, w1t, w2t,
                                       Wg, bg, Wp, bp, Wgg, bgg,
                                       e0a, e1a, w0a, w1a);
  k_bucket<<<NB / 256, 256, 0, stream>>>(e0a, e1a, w0a, w1a, rowl, wl, cnt,
                                         pos0a, pos1a, rowlp, cntp,
                                         tkt, pb, i16b, i16m, n16, ipp, ipm, np);
  // n16 worst case: 16384/128 + 16 partial tiles = 144; BN=256 -> grid.x = 2
  k_gemm1<<<dim3(2, 144, 1), 256, 0, stream>>>(xh, w1t, b1, rowl, wl, cnt, pb,
                                               i16b, i16m, n16, Hbuf);
  // np worst case: 8192/128 + 64 partial tiles = 128; BN=128 -> grid.x = 16
  k_gemm2p<<<dim3(16, 128, 1), 256, 0, stream>>>(Hbuf, w2t, b2, rowlp, cntp, pb,
                                                 pos0a, pos1a, w0a, w1a, ipp, ipm, np, out);
}

// Round 8
// 327.550 us; speedup vs baseline: 1.2850x; 1.0170x over previous
//
#include <hip/hip_runtime.h>
#include <stdint.h>

#define NB 8192
#define ND 2048
#define NE 8
#define NG 4
#define NP 512
#define NH 192

typedef _Float16 half_t;
typedef half_t f16x8 __attribute__((ext_vector_type(8)));
typedef float f32x4 __attribute__((ext_vector_type(4)));

__device__ __forceinline__ void gload16(const void* g, void* l) {
  __builtin_amdgcn_global_load_lds(
      (const __attribute__((address_space(1))) void*)g,
      (__attribute__((address_space(3))) void*)l, 16, 0, 0);
}

// ---------------- fused pre-pass (R7, verified) ----------------
__global__ __launch_bounds__(256) void k_pre(
    const float* __restrict__ x, half_t* __restrict__ xh,
    const float* __restrict__ W1, const float* __restrict__ W2,
    half_t* __restrict__ w1t, half_t* __restrict__ w2t,
    const float* __restrict__ Wg, const float* __restrict__ bg,
    const float* __restrict__ Wp, const float* __restrict__ bp,
    const float* __restrict__ Wgg, const float* __restrict__ bgg,
    int* __restrict__ e0a, int* __restrict__ e1a,
    float* __restrict__ w0a, float* __restrict__ w1a)
{
  const int t = threadIdx.x;

  if (blockIdx.x >= NB) {
    int id = blockIdx.x - NB;
    const int which = id >> 12;
    id &= 4095;
    const int R = which ? NP : ND;
    const int C = which ? ND : NP;
    const float* src = which ? W2 : W1;
    half_t* dst = which ? w2t : w1t;
    const int tiles_c = C >> 5;
    const int tiles_per_e = (R >> 6) * tiles_c;
    int e = id / tiles_per_e;
    int rem = id - e * tiles_per_e;
    int tr = rem / tiles_c, tc = rem - tr * tiles_c;
    __shared__ float tile[64][33];
    const int lc = t & 31, lr = t >> 5;
    const float* s = src + (size_t)e * R * C + (size_t)(tr * 64) * C + tc * 32;
#pragma unroll
    for (int i = 0; i < 8; i++)
      tile[lr + i * 8][lc] = s[(size_t)(lr + i * 8) * C + lc];
    __syncthreads();
    const int n = t >> 3, kc = (t & 7) * 8;
    __align__(16) half_t hb[8];
#pragma unroll
    for (int j = 0; j < 8; j++) hb[j] = (half_t)tile[kc + j][n];
    half_t* d = dst + (size_t)e * R * C + (size_t)(tc * 32 + n) * R + tr * 64 + kc;
    *reinterpret_cast<int4*>(d) = *reinterpret_cast<const int4*>(hb);
    return;
  }

  const int b = blockIdx.x;
  const float* xr = x + (size_t)b * ND;
  const float4 v0 = ((const float4*)xr)[t * 2];
  const float4 v1 = ((const float4*)xr)[t * 2 + 1];
  float f[8] = {v0.x, v0.y, v0.z, v0.w, v1.x, v1.y, v1.z, v1.w};
  double s = 0.0;
  __align__(16) half_t hb[8];
#pragma unroll
  for (int i = 0; i < 8; i++) { s += (double)f[i]; hb[i] = (half_t)f[i]; }
  *reinterpret_cast<int4*>(xh + (size_t)b * ND + t * 8) = *reinterpret_cast<const int4*>(hb);

#pragma unroll
  for (int m = 32; m >= 1; m >>= 1) s += __shfl_xor(s, m);
  __shared__ double part[4];
  __shared__ double qm_s;
  if ((t & 63) == 0) part[t >> 6] = s;
  __syncthreads();
  if (t == 0) qm_s = (part[0] + part[1] + part[2] + part[3]) / (double)ND;
  __syncthreads();

  const double q = qm_s;
  double g = 0.0;
  if (t < 192) {
    double ang = q * (7.0 * (double)(t + 1));
    g = cos(ang) + sin(ang);
  }
#pragma unroll
  for (int m = 32; m >= 1; m >>= 1) g += __shfl_xor(g, m);
  __shared__ double gp[4];
  if ((t & 63) == 0) gp[t >> 6] = g;
  __syncthreads();

  if (t < 64) {
    const double tm = (gp[0] + gp[1] + gp[2] + gp[3]) / (2.0 * (double)NH);
    const double gi1 = 32.0 / 2048.0;
    double lg = -1.0e300;
    if (t < 8) {
      const int e = t, gg = e & 3;
      lg = tm * (double)Wg[e] + gi1 * (double)Wg[NE + e] + (double)bg[e];
      lg -= 0.1 * (tm * (double)Wp[e] + gi1 * (double)Wp[NE + e] + (double)bp[e]);
      lg += tm * (double)Wgg[gg] + gi1 * (double)Wgg[NG + gg] + (double)bgg[gg];
    }
    double mx = lg;
#pragma unroll
    for (int m = 4; m >= 1; m >>= 1) mx = fmax(mx, __shfl_xor(mx, m));
    double pe = 0.0;
    if (t < 8) pe = exp(lg - mx);
    double ps = pe;
#pragma unroll
    for (int m = 4; m >= 1; m >>= 1) ps += __shfl_xor(ps, m);

    double lgs[8], pes[8];
#pragma unroll
    for (int e = 0; e < 8; e++) { lgs[e] = __shfl(lg, e); pes[e] = __shfl(pe, e); }

    if (t == 0) {
      int e0 = 0;
      for (int e = 1; e < NE; e++) if (lgs[e] > lgs[e0]) e0 = e;
      int e1 = (e0 == 0) ? 1 : 0;
      for (int e = 0; e < NE; e++) if (e != e0 && lgs[e] > lgs[e1]) e1 = e;
      const double p0 = pes[e0] / ps;
      const double p1 = pes[e1] / ps;
      const double den = p0 + p1 + 1e-9;
      e0a[b] = e0; e1a[b] = e1;
      w0a[b] = (float)(p0 / den);
      w1a[b] = (float)(p1 / den);
    }
  }
}

// ---------------- bucket build + fused prefix (R7, verified) ----------------
__global__ __launch_bounds__(256) void k_bucket(
    const int* __restrict__ e0a, const int* __restrict__ e1a,
    const float* __restrict__ w0a, const float* __restrict__ w1a,
    int* __restrict__ rowl, float* __restrict__ wl, int* __restrict__ cnt,
    int* __restrict__ pos0a, int* __restrict__ pos1a,
    int* __restrict__ rowlp, int* __restrict__ cntp,
    int* __restrict__ ticket, int* __restrict__ pbase,
    int* __restrict__ i16b, int* __restrict__ i16m, int* __restrict__ n16,
    int* __restrict__ ipp, int* __restrict__ ipm, int* __restrict__ np)
{
  const int t = threadIdx.x;
  const int r = blockIdx.x * 256 + t;
  __shared__ int hist[16], base[16], cursor[16];
  __shared__ int histp[64], basep[64], cursorp[64];
  __shared__ int lastf;
  if (t < 16) { hist[t] = 0; cursor[t] = 0; }
  if (t < 64) { histp[t] = 0; cursorp[t] = 0; }
  __syncthreads();

  const int e0 = e0a[r], e1 = e1a[r];
  const int p = e0 * 8 + e1;
  atomicAdd(&hist[e0], 1);
  atomicAdd(&hist[8 + e1], 1);
  atomicAdd(&histp[p], 1);
  __syncthreads();
  if (t < 16) base[t] = atomicAdd(&cnt[t], hist[t]);
  if (t < 64) basep[t] = atomicAdd(&cntp[t], histp[t]);
  __syncthreads();

  int p0 = atomicAdd(&cursor[e0], 1);
  int idx0 = base[e0] + p0;
  rowl[e0 * NB + idx0] = r;
  wl[e0 * NB + idx0] = w0a[r];
  pos0a[r] = idx0;

  int p1 = atomicAdd(&cursor[8 + e1], 1);
  int idx1 = base[8 + e1] + p1;
  rowl[(8 + e1) * NB + idx1] = r;
  wl[(8 + e1) * NB + idx1] = w1a[r];
  pos1a[r] = idx1;

  int pp = atomicAdd(&cursorp[p], 1);
  rowlp[p * NB + basep[p] + pp] = r;

  __threadfence();
  __syncthreads();
  if (t == 0) lastf = (atomicAdd(ticket, 1) == (int)gridDim.x - 1);
  __syncthreads();
  if (lastf) {
    if (t == 0) {
      int c[16];
#pragma unroll
      for (int i = 0; i < 16; i++) c[i] = atomicAdd(&cnt[i], 0);
      int s = 0;
#pragma unroll
      for (int i = 0; i < 16; i++) { pbase[i] = s; s += c[i]; }
      int k = 0;
      for (int bb = 0; bb < 16; bb++)
        for (int m0 = 0; m0 < c[bb]; m0 += 128) { i16b[k] = bb; i16m[k] = m0; k++; }
      *n16 = k;
    } else if (t == 64) {
      int c[64];
#pragma unroll
      for (int i = 0; i < 64; i++) c[i] = atomicAdd(&cntp[i], 0);
      int k = 0;
      for (int pq = 0; pq < 64; pq++)
        for (int m0 = 0; m0 < c[pq]; m0 += 128) { ipp[k] = pq; ipm[k] = m0; k++; }
      *np = k;
    }
  }
}

// ---------------- GEMM1: H = w * relu(gather(x) @ W1[e] + b1[e]) ----------------
// R8: 512 threads / 8 waves per block (was 4). Same BM=128/BN=256 tile and
// byte-identical traffic (~430MB, the floor), but wave tile 64x64 (acc 4x4,
// ~110 VGPR) -> 2 blocks/CU x 8 waves = 16 waves/CU (R7 counter: Occupancy
// 9.7%, 1.1 waves/SIMD -- latency had no cover). Staging: 3 wave-loads/stage
// (1 A + 2 B), steady s_waitcnt vmcnt(3), same 3-buf rotation + chunk swizzle.
__global__ __launch_bounds__(512, 4) void k_gemm1(
    const half_t* __restrict__ xh, const half_t* __restrict__ w1t,
    const float* __restrict__ b1,
    const int* __restrict__ rowl, const float* __restrict__ wl,
    const int* __restrict__ cnt, const int* __restrict__ pbase,
    const int* __restrict__ i16b, const int* __restrict__ i16m,
    const int* __restrict__ n16, half_t* __restrict__ Hbuf)
{
  const int wi = blockIdx.y;
  if (wi >= *n16) return;
  const int bucket = i16b[wi];
  const int m0 = i16m[wi];
  const int count = cnt[bucket];
  const int e = bucket & 7;
  const int n0 = blockIdx.x * 256;
  const int t = threadIdx.x;

  __shared__ __align__(16) half_t As[3][128 * 32];   // 3 x 8KB
  __shared__ __align__(16) half_t Bs[3][256 * 32];   // 3 x 16KB
  __shared__ int rows_s[128];
  __shared__ float ws_s[128];

  if (t < 128) {
    int mi = m0 + t;
    int idx = bucket * NB + (mi < count ? mi : m0);
    rows_s[t] = rowl[idx];
    ws_s[t] = wl[idx];
  }
  __syncthreads();

  const int w = t >> 6, lane = t & 63;
  // A: wave w stages rows [16w, 16w+16) in ONE wave-load (64 lanes x 16B)
  const int rA = w * 16 + (lane >> 2);
  const int kA = ((lane & 3) ^ ((rA >> 1) & 3)) * 8;
  const half_t* gA = xh + (size_t)rows_s[rA] * ND + kA;
  // B: wave w stages rows [32w, 32w+32) in TWO wave-loads
  const half_t* w1te = w1t + (size_t)e * NP * ND;
  const int rB0 = w * 32 + (lane >> 2), rB1 = rB0 + 16;
  const int kB0 = ((lane & 3) ^ ((rB0 >> 1) & 3)) * 8;
  const int kB1 = ((lane & 3) ^ ((rB1 >> 1) & 3)) * 8;
  const half_t* gB0 = w1te + (size_t)(n0 + rB0) * ND + kB0;
  const half_t* gB1 = w1te + (size_t)(n0 + rB1) * ND + kB1;

  const int wr = w >> 2, wn = w & 3;      // 2m x 4n wave grid, 64x64 each
  const int lrow = lane & 15, lk = lane >> 4;
  const int lko = (lk ^ ((lrow >> 1) & 3)) * 8;

  f32x4 acc[4][4];
#pragma unroll
  for (int i = 0; i < 4; i++)
#pragma unroll
    for (int j = 0; j < 4; j++) {
      acc[i][j][0] = 0.f; acc[i][j][1] = 0.f; acc[i][j][2] = 0.f; acc[i][j][3] = 0.f;
    }

  auto stage = [&](int bi, int tt) {
    const int kk = tt * 32;
    gload16(gA + kk, &As[bi][w * 512]);
    gload16(gB0 + kk, &Bs[bi][w * 1024]);
    gload16(gB1 + kk, &Bs[bi][w * 1024 + 512]);
  };
  auto compute = [&](int bi) {
    f16x8 af[4], bf[4];
#pragma unroll
    for (int i = 0; i < 4; i++)
      af[i] = *reinterpret_cast<const f16x8*>(&As[bi][(wr * 64 + i * 16 + lrow) * 32 + lko]);
#pragma unroll
    for (int n = 0; n < 4; n++)
      bf[n] = *reinterpret_cast<const f16x8*>(&Bs[bi][(wn * 64 + n * 16 + lrow) * 32 + lko]);
#pragma unroll
    for (int mi = 0; mi < 4; mi++)
#pragma unroll
      for (int ni = 0; ni < 4; ni++)
        acc[mi][ni] = __builtin_amdgcn_mfma_f32_16x16x32_f16(af[mi], bf[ni], acc[mi][ni], 0, 0, 0);
  };

  // 64 rounds, 3 loads/wave/stage -> steady vmcnt(3)
  stage(0, 0);
  stage(1, 1);
  asm volatile("s_waitcnt vmcnt(3)" ::: "memory");
  __builtin_amdgcn_s_barrier();
  for (int t3 = 0; t3 < 60; t3 += 3) {
    stage(2, t3 + 2); compute(0);
    asm volatile("s_waitcnt vmcnt(3) lgkmcnt(0)" ::: "memory");
    __builtin_amdgcn_s_barrier();
    stage(0, t3 + 3); compute(1);
    asm volatile("s_waitcnt vmcnt(3) lgkmcnt(0)" ::: "memory");
    __builtin_amdgcn_s_barrier();
    stage(1, t3 + 4); compute(2);
    asm volatile("s_waitcnt vmcnt(3) lgkmcnt(0)" ::: "memory");
    __builtin_amdgcn_s_barrier();
  }
  stage(2, 62); compute(0);
  asm volatile("s_waitcnt vmcnt(3) lgkmcnt(0)" ::: "memory");
  __builtin_amdgcn_s_barrier();
  stage(0, 63); compute(1);
  asm volatile("s_waitcnt vmcnt(3) lgkmcnt(0)" ::: "memory");
  __builtin_amdgcn_s_barrier();
  compute(2);
  asm volatile("s_waitcnt vmcnt(0) lgkmcnt(0)" ::: "memory");
  __builtin_amdgcn_s_barrier();
  compute(0);

  const int pb = pbase[bucket];
#pragma unroll
  for (int mi = 0; mi < 4; mi++) {
#pragma unroll
    for (int i = 0; i < 4; i++) {
      int lm = wr * 64 + mi * 16 + lk * 4 + i;
      if (m0 + lm < count) {
        size_t prow = (size_t)(pb + m0 + lm) * NP;
        float wcoef = ws_s[lm];
#pragma unroll
        for (int ni = 0; ni < 4; ni++) {
          int col = n0 + wn * 64 + ni * 16 + lrow;
          float v = acc[mi][ni][i] + b1[e * NP + col];
          v = v > 0.f ? v : 0.f;
          Hbuf[prow + col] = (half_t)(v * wcoef);  // pre-scale by gate weight
        }
      }
    }
  }
}

// ---- GEMM2 (pair-fused): out[r] = H0w@W2[e0] + H1w@W2[e1] + w0*b2[e0] + w1*b2[e1] ----
// R8: same 8-wave restructure, BN=256 (grid.x 16->8; traffic 536->405MB).
// R5's BN=256 failure was 8 waves/CU with no in-block parallelism; this has
// 16 waves/CU. NT=32 (2 segs x 16 x BK=32), full NP=512 per segment.
__global__ __launch_bounds__(512, 4) void k_gemm2p(
    const half_t* __restrict__ Hbuf, const half_t* __restrict__ w2t,
    const float* __restrict__ b2,
    const int* __restrict__ rowlp, const int* __restrict__ cntp,
    const int* __restrict__ pbase,
    const int* __restrict__ pos0a, const int* __restrict__ pos1a,
    const float* __restrict__ w0a, const float* __restrict__ w1a,
    const int* __restrict__ ipp, const int* __restrict__ ipm,
    const int* __restrict__ np, float* __restrict__ out)
{
  const int wi = blockIdx.y;
  if (wi >= *np) return;
  const int p = ipp[wi];
  const int m0 = ipm[wi];
  const int count = cntp[p];
  const int e0 = p >> 3, e1 = p & 7;
  const int n0 = blockIdx.x * 256;
  const int t = threadIdx.x;

  __shared__ __align__(16) half_t As[3][128 * 32];
  __shared__ __align__(16) half_t Bs[3][256 * 32];
  __shared__ int h0_s[128], h1_s[128], rs_s[128];
  __shared__ float w0_s[128], w1_s[128];

  if (t < 128) {
    int mi = m0 + t;
    int r = rowlp[p * NB + (mi < count ? mi : m0)];
    rs_s[t] = r;
    h0_s[t] = pbase[e0] + pos0a[r];
    h1_s[t] = pbase[8 + e1] + pos1a[r];
    w0_s[t] = w0a[r];
    w1_s[t] = w1a[r];
  }
  __syncthreads();

  const int w = t >> 6, lane = t & 63;
  const int rA = w * 16 + (lane >> 2);
  const int kA = ((lane & 3) ^ ((rA >> 1) & 3)) * 8;
  const half_t* sa0 = Hbuf + (size_t)h0_s[rA] * NP + kA;
  const half_t* sa1 = Hbuf + (size_t)h1_s[rA] * NP + kA;

  const half_t* w2e0 = w2t + (size_t)e0 * ND * NP;
  const half_t* w2e1 = w2t + (size_t)e1 * ND * NP;
  const int rB0 = w * 32 + (lane >> 2), rB1 = rB0 + 16;
  const int kB0 = ((lane & 3) ^ ((rB0 >> 1) & 3)) * 8;
  const int kB1 = ((lane & 3) ^ ((rB1 >> 1) & 3)) * 8;
  const half_t* pB00 = w2e0 + (size_t)(n0 + rB0) * NP + kB0;
  const half_t* pB01 = w2e0 + (size_t)(n0 + rB1) * NP + kB1;
  const half_t* pB10 = w2e1 + (size_t)(n0 + rB0) * NP + kB0;
  const half_t* pB11 = w2e1 + (size_t)(n0 + rB1) * NP + kB1;

  const int wr = w >> 2, wn = w & 3;
  const int lrow = lane & 15, lk = lane >> 4;
  const int lko = (lk ^ ((lrow >> 1) & 3)) * 8;

  f32x4 acc[4][4];
#pragma unroll
  for (int i = 0; i < 4; i++)
#pragma unroll
    for (int j = 0; j < 4; j++) {
      acc[i][j][0] = 0.f; acc[i][j][1] = 0.f; acc[i][j][2] = 0.f; acc[i][j][3] = 0.f;
    }

  const int NT = 32;

  auto stage = [&](int bi, int tt) {
    const int kk = (tt & 15) * 32;
    if (tt & 16) {
      gload16(sa1 + kk, &As[bi][w * 512]);
      gload16(pB10 + kk, &Bs[bi][w * 1024]);
      gload16(pB11 + kk, &Bs[bi][w * 1024 + 512]);
    } else {
      gload16(sa0 + kk, &As[bi][w * 512]);
      gload16(pB00 + kk, &Bs[bi][w * 1024]);
      gload16(pB01 + kk, &Bs[bi][w * 1024 + 512]);
    }
  };
  auto compute = [&](int bi) {
    f16x8 af[4], bf[4];
#pragma unroll
    for (int i = 0; i < 4; i++)
      af[i] = *reinterpret_cast<const f16x8*>(&As[bi][(wr * 64 + i * 16 + lrow) * 32 + lko]);
#pragma unroll
    for (int n = 0; n < 4; n++)
      bf[n] = *reinterpret_cast<const f16x8*>(&Bs[bi][(wn * 64 + n * 16 + lrow) * 32 + lko]);
#pragma unroll
    for (int mi = 0; mi < 4; mi++)
#pragma unroll
      for (int ni = 0; ni < 4; ni++)
        acc[mi][ni] = __builtin_amdgcn_mfma_f32_16x16x32_f16(af[mi], bf[ni], acc[mi][ni], 0, 0, 0);
  };

  stage(0, 0);
  stage(1, 1);
  asm volatile("s_waitcnt vmcnt(3)" ::: "memory");
  __builtin_amdgcn_s_barrier();
#pragma unroll
  for (int tt = 0; tt < NT; ++tt) {
    if (tt + 2 < NT) stage((tt + 2) % 3, tt + 2);
    compute(tt % 3);
    if (tt + 1 < NT) {
      if (tt + 2 < NT) asm volatile("s_waitcnt vmcnt(3) lgkmcnt(0)" ::: "memory");
      else             asm volatile("s_waitcnt vmcnt(0) lgkmcnt(0)" ::: "memory");
      __builtin_amdgcn_s_barrier();
    }
  }

  float b20[4], b21[4];
#pragma unroll
  for (int ni = 0; ni < 4; ni++) {
    int col = n0 + wn * 64 + ni * 16 + lrow;
    b20[ni] = b2[e0 * ND + col];
    b21[ni] = b2[e1 * ND + col];
  }
#pragma unroll
  for (int mi = 0; mi < 4; mi++) {
#pragma unroll
    for (int i = 0; i < 4; i++) {
      int lm = wr * 64 + mi * 16 + lk * 4 + i;
      if (m0 + lm < count) {
        int r = rs_s[lm];
        float wb0 = w0_s[lm], wb1 = w1_s[lm];
        float* orow = out + (size_t)r * ND;
#pragma unroll
        for (int ni = 0; ni < 4; ni++) {
          int col = n0 + wn * 64 + ni * 16 + lrow;
          orow[col] = acc[mi][ni][i] + wb0 * b20[ni] + wb1 * b21[ni];
        }
      }
    }
  }
}

extern "C" void kernel_launch(void* const* d_in, const int* in_sizes, int n_in,
                              void* d_out, int out_size, void* d_ws, size_t ws_size,
                              hipStream_t stream)
{
  const float* x   = (const float*)d_in[0];
  const float* Wg  = (const float*)d_in[1];
  const float* bg  = (const float*)d_in[2];
  const float* Wp  = (const float*)d_in[3];
  const float* bp  = (const float*)d_in[4];
  const float* Wgg = (const float*)d_in[5];
  const float* bgg = (const float*)d_in[6];
  const float* W1  = (const float*)d_in[7];
  const float* b1  = (const float*)d_in[8];
  const float* W2  = (const float*)d_in[9];
  const float* b2  = (const float*)d_in[10];
  float* out = (float*)d_out;

  char* ws = (char*)d_ws;
  size_t off = 0;
  const size_t OFF_XH   = off; off += (size_t)NB * ND * 2;              // 32 MB
  const size_t OFF_W1T  = off; off += (size_t)NE * NP * ND * 2;         // 16 MB
  const size_t OFF_W2T  = off; off += (size_t)NE * ND * NP * 2;         // 16 MB
  const size_t OFF_H    = off; off += (size_t)(2 * NB + 128) * NP * 2;  // ~17 MB
  const size_t OFF_ROWL = off; off += (size_t)16 * NB * 4;
  const size_t OFF_WL   = off; off += (size_t)16 * NB * 4;
  const size_t OFF_ROWLP= off; off += (size_t)64 * NB * 4;              // 2 MB
  const size_t OFF_CNT  = off; off += 64;
  const size_t OFF_CNTP = off; off += 256;
  const size_t OFF_TKT  = off; off += 64;
  const size_t OFF_PB   = off; off += 64;
  const size_t OFF_E0   = off; off += (size_t)NB * 4;
  const size_t OFF_E1   = off; off += (size_t)NB * 4;
  const size_t OFF_W0   = off; off += (size_t)NB * 4;
  const size_t OFF_W1A  = off; off += (size_t)NB * 4;
  const size_t OFF_POS0 = off; off += (size_t)NB * 4;
  const size_t OFF_POS1 = off; off += (size_t)NB * 4;
  const size_t OFF_I16B = off; off += 1024;
  const size_t OFF_I16M = off; off += 1024;
  const size_t OFF_N16  = off; off += 64;
  const size_t OFF_IPP  = off; off += 1024;
  const size_t OFF_IPM  = off; off += 1024;
  const size_t OFF_NP   = off; off += 64;

  half_t* xh   = (half_t*)(ws + OFF_XH);
  half_t* w1t  = (half_t*)(ws + OFF_W1T);
  half_t* w2t  = (half_t*)(ws + OFF_W2T);
  half_t* Hbuf = (half_t*)(ws + OFF_H);
  int*    rowl = (int*)(ws + OFF_ROWL);
  float*  wl   = (float*)(ws + OFF_WL);
  int*    rowlp= (int*)(ws + OFF_ROWLP);
  int*    cnt  = (int*)(ws + OFF_CNT);
  int*    cntp = (int*)(ws + OFF_CNTP);
  int*    tkt  = (int*)(ws + OFF_TKT);
  int*    pb   = (int*)(ws + OFF_PB);
  int*    e0a  = (int*)(ws + OFF_E0);
  int*    e1a  = (int*)(ws + OFF_E1);
  float*  w0a  = (float*)(ws + OFF_W0);
  float*  w1a  = (float*)(ws + OFF_W1A);
  int*    pos0a= (int*)(ws + OFF_POS0);
  int*    pos1a= (int*)(ws + OFF_POS1);
  int*    i16b = (int*)(ws + OFF_I16B);
  int*    i16m = (int*)(ws + OFF_I16M);
  int*    n16  = (int*)(ws + OFF_N16);
  int*    ipp  = (int*)(ws + OFF_IPP);
  int*    ipm  = (int*)(ws + OFF_IPM);
  int*    np   = (int*)(ws + OFF_NP);

  hipMemsetAsync(cnt, 0, 64 + 256 + 64, stream);
  k_pre<<<NB + 8192, 256, 0, stream>>>(x, xh, W1, W2, w1t, w2t,
                                       Wg, bg, Wp, bp, Wgg, bgg,
                                       e0a, e1a, w0a, w1a);
  k_bucket<<<NB / 256, 256, 0, stream>>>(e0a, e1a, w0a, w1a, rowl, wl, cnt,
                                         pos0a, pos1a, rowlp, cntp,
                                         tkt, pb, i16b, i16m, n16, ipp, ipm, np);
  // n16 worst case 144; BN=256 -> grid.x = 2
  k_gemm1<<<dim3(2, 144, 1), 512, 0, stream>>>(xh, w1t, b1, rowl, wl, cnt, pb,
                                               i16b, i16m, n16, Hbuf);
  // np worst case 128; BN=256 -> grid.x = 8
  k_gemm2p<<<dim3(8, 128, 1), 512, 0, stream>>>(Hbuf, w2t, b2, rowlp, cntp, pb,
                                                 pos0a, pos1a, w0a, w1a, ipp, ipm, np, out);
}